// Round 3
// baseline (546.774 us; speedup 1.0000x reference)
//
#include <hip/hip_runtime.h>
#include <math.h>

// ---------------------------------------------------------------------------
// GNN link predictor: 2-layer GraphSAGE (mean agg) + dot-product + sigmoid.
// Restructurings:
//  - transform-then-aggregate (mean is linear) -> aggregate in 64-dim space
//  - CSR-by-dst built per call; scatter is ATOMIC-FREE (rank = histogram
//    atomic return value)
//  - wave-per-node pull aggregation (lane = channel, coalesced 256B rows)
//  - R3 GEMM rewrite: K chunked to 64 (35.8KB LDS -> 4 blocks/CU vs 2),
//    skewed LDS layout phys(c)=c+4*(c>>5) makes W reads 2-way (free) instead
//    of 4-way (was 3.1e7 conflict cycles), 8x8 per-thread tile keeps the
//    LDS pipe under the VALU demand at 16 waves/CU.
// ---------------------------------------------------------------------------

#define HID 64
#define WSTRIDE 140  // 64 rows x 140 floats = 35,840 B LDS; 140%32=12, rows 16B-aligned

// ---------------- CSR build ----------------

__global__ __launch_bounds__(256)
void k_hist(const int* __restrict__ edst, int* __restrict__ deg,
            int* __restrict__ rank, int E) {
    int e = blockIdx.x * 256 + threadIdx.x;
    if (e < E) rank[e] = atomicAdd(&deg[edst[e]], 1);
}

__global__ __launch_bounds__(256)
void k_scan1(const int* __restrict__ deg, int* __restrict__ offs,
             int* __restrict__ bsums, int n) {
    __shared__ int lds[256];
    int t = threadIdx.x;
    int base = blockIdx.x * 1024 + t * 4;
    int v0 = 0, v1 = 0, v2 = 0, v3 = 0;
    if (base + 0 < n) v0 = deg[base + 0];
    if (base + 1 < n) v1 = deg[base + 1];
    if (base + 2 < n) v2 = deg[base + 2];
    if (base + 3 < n) v3 = deg[base + 3];
    int ts = v0 + v1 + v2 + v3;
    lds[t] = ts;
    __syncthreads();
    for (int off = 1; off < 256; off <<= 1) {
        int x = (t >= off) ? lds[t - off] : 0;
        __syncthreads();
        lds[t] += x;
        __syncthreads();
    }
    int excl = lds[t] - ts;
    if (base + 0 < n) offs[base + 0] = excl;
    if (base + 1 < n) offs[base + 1] = excl + v0;
    if (base + 2 < n) offs[base + 2] = excl + v0 + v1;
    if (base + 3 < n) offs[base + 3] = excl + v0 + v1 + v2;
    if (t == 255) bsums[blockIdx.x] = lds[255];
}

__global__ __launch_bounds__(256)
void k_scan2(int* __restrict__ bsums, int nb) {
    __shared__ int lds[256];
    int t = threadIdx.x;
    int v = (t < nb) ? bsums[t] : 0;
    lds[t] = v;
    __syncthreads();
    for (int off = 1; off < 256; off <<= 1) {
        int x = (t >= off) ? lds[t - off] : 0;
        __syncthreads();
        lds[t] += x;
        __syncthreads();
    }
    if (t < nb) bsums[t] = lds[t] - v;
}

__global__ __launch_bounds__(256)
void k_scan3(int* __restrict__ offs, const int* __restrict__ bsums, int n) {
    int i = blockIdx.x * 256 + threadIdx.x;
    if (i < n) offs[i] += bsums[i >> 10];
}

__global__ __launch_bounds__(256)
void k_scatter(const int* __restrict__ esrc, const int* __restrict__ edst,
               const int* __restrict__ offs, const int* __restrict__ rank,
               int* __restrict__ sorted, int E) {
    int e = blockIdx.x * 256 + threadIdx.x;
    if (e < E) {
        int d = edst[e];
        sorted[offs[d] + rank[e]] = esrc[e];
    }
}

// ---------------- dual GEMM: P = X@Wl^T, Q = X@Wr^T (both 64 x K) ----------------
// 256 thr, 128 rows/block, thread = 8 rows x 8 cols. W staged transposed in
// LDS with skew phys(c) = c + 4*(c>>5) (reads AND writes 2-way -> free).
// K chunked by 64 -> 35.8 KB LDS -> 4 blocks/CU.

__device__ __forceinline__ float f4get(const float4& v, int k) {
    return k == 0 ? v.x : k == 1 ? v.y : k == 2 ? v.z : v.w;
}

template <int K>
__global__ __launch_bounds__(256, 4)
void gemm_dual(const float* __restrict__ X, const float* __restrict__ Wl,
               const float* __restrict__ Wr, float* __restrict__ P,
               float* __restrict__ Qo, int N) {
    __shared__ float sW[64 * WSTRIDE];
    const int t = threadIdx.x;
    const int og = t & 15;   // 8-col group
    const int rg = t >> 4;   // 16 groups x 8 rows = 128 rows
    const int rbase = blockIdx.x * 128 + rg * 8;
    const int cskew = og * 8 + ((og >> 2) << 2);  // phys(og*8)

    int rowoff[8];
    bool ok[8];
#pragma unroll
    for (int i = 0; i < 8; ++i) {
        int r = rbase + i;
        ok[i] = (r < N);
        rowoff[i] = (ok[i] ? r : 0) * K;
    }

    float acc[8][8];
#pragma unroll
    for (int i = 0; i < 8; ++i)
#pragma unroll
        for (int j = 0; j < 8; ++j) acc[i][j] = 0.f;

    for (int k0 = 0; k0 < K; k0 += 64) {
        if (k0) __syncthreads();
        // stage 128 cols x 64 k of [Wl|Wr]^T. task tau: c_lo=tau&31 (bank
        // spread), k4=(tau>>5)&15 (float4 along k), c_hi=tau>>9 (wave-uniform).
#pragma unroll
        for (int m = 0; m < 8; ++m) {
            int tau = t + 256 * m;
            int c = (tau & 31) + ((tau >> 9) << 5);
            int k4 = (tau >> 5) & 15;
            const float* gsrc = (c < 64) ? (Wl + c * K + k0 + (k4 << 2))
                                         : (Wr + (c - 64) * K + k0 + (k4 << 2));
            float4 w = *(const float4*)gsrc;
            int base = (k4 << 2) * WSTRIDE + c + ((c >> 5) << 2);
            sW[base] = w.x;
            sW[base + WSTRIDE] = w.y;
            sW[base + 2 * WSTRIDE] = w.z;
            sW[base + 3 * WSTRIDE] = w.w;
        }
        __syncthreads();

        for (int kk4 = 0; kk4 < 64; kk4 += 4) {
            float4 w0[4], w1[4];
#pragma unroll
            for (int kk = 0; kk < 4; ++kk) {
                const float* wr_ = &sW[(kk4 + kk) * WSTRIDE + cskew];
                w0[kk] = *(const float4*)wr_;
                w1[kk] = *(const float4*)(wr_ + 4);
            }
#pragma unroll
            for (int i = 0; i < 8; ++i) {
                float4 xr = *(const float4*)(X + (size_t)rowoff[i] + k0 + kk4);
#pragma unroll
                for (int kk = 0; kk < 4; ++kk) {
                    float xs = f4get(xr, kk);
                    acc[i][0] = fmaf(xs, w0[kk].x, acc[i][0]);
                    acc[i][1] = fmaf(xs, w0[kk].y, acc[i][1]);
                    acc[i][2] = fmaf(xs, w0[kk].z, acc[i][2]);
                    acc[i][3] = fmaf(xs, w0[kk].w, acc[i][3]);
                    acc[i][4] = fmaf(xs, w1[kk].x, acc[i][4]);
                    acc[i][5] = fmaf(xs, w1[kk].y, acc[i][5]);
                    acc[i][6] = fmaf(xs, w1[kk].z, acc[i][6]);
                    acc[i][7] = fmaf(xs, w1[kk].w, acc[i][7]);
                }
            }
        }
    }

    float* dstp = (og < 8) ? P : Qo;
    const int cb = (og < 8) ? og * 8 : og * 8 - 64;
#pragma unroll
    for (int i = 0; i < 8; ++i) {
        if (ok[i]) {
            float* p = dstp + (size_t)(rbase + i) * HID + cb;
            *(float4*)p = make_float4(acc[i][0], acc[i][1], acc[i][2], acc[i][3]);
            *(float4*)(p + 4) = make_float4(acc[i][4], acc[i][5], acc[i][6], acc[i][7]);
        }
    }
}

// ---------------- aggregation: H = relu(mean_{s in N(n)} P[s] + bias + Qin[n]) ----

__global__ __launch_bounds__(256)
void k_agg(const float* __restrict__ P, const float* Qin,
           const float* __restrict__ bias, const int* __restrict__ offs,
           const int* __restrict__ deg, const int* __restrict__ sorted,
           float* H, int N) {
    int wid = blockIdx.x * 4 + (threadIdx.x >> 6);
    int lane = threadIdx.x & 63;
    if (wid >= N) return;
    int off = __builtin_amdgcn_readfirstlane(offs[wid]);
    int c = __builtin_amdgcn_readfirstlane(deg[wid]);
    float acc = 0.f;
    int i = 0;
    for (; i + 3 < c; i += 4) {
        int s0 = sorted[off + i];
        int s1 = sorted[off + i + 1];
        int s2 = sorted[off + i + 2];
        int s3 = sorted[off + i + 3];
        float a0 = P[(size_t)s0 * HID + lane];
        float a1 = P[(size_t)s1 * HID + lane];
        float a2 = P[(size_t)s2 * HID + lane];
        float a3 = P[(size_t)s3 * HID + lane];
        acc += (a0 + a1) + (a2 + a3);
    }
    for (; i < c; ++i) acc += P[(size_t)sorted[off + i] * HID + lane];
    float inv = 1.0f / (float)(c > 0 ? c : 1);
    float v = acc * inv + bias[lane] + Qin[(size_t)wid * HID + lane];
    H[(size_t)wid * HID + lane] = v > 0.f ? v : 0.f;
}

// ---------------- query ----------------

__global__ __launch_bounds__(256)
void k_query(const float* __restrict__ Z, const int* __restrict__ src,
             const int* __restrict__ dst, float* __restrict__ out, int Q) {
    int q = blockIdx.x * 4 + (threadIdx.x >> 6);
    int lane = threadIdx.x & 63;
    if (q >= Q) return;
    int s = __builtin_amdgcn_readfirstlane(src[q]);
    int d = __builtin_amdgcn_readfirstlane(dst[q]);
    float v = Z[(size_t)s * HID + lane] * Z[(size_t)d * HID + lane];
#pragma unroll
    for (int m = 32; m > 0; m >>= 1) v += __shfl_xor(v, m, 64);
    if (lane == 0) out[q] = 1.0f / (1.0f + __expf(-v));
}

// ---------------- launch ----------------

extern "C" void kernel_launch(void* const* d_in, const int* in_sizes, int n_in,
                              void* d_out, int out_size, void* d_ws, size_t ws_size,
                              hipStream_t stream) {
    const float* x    = (const float*)d_in[0];
    const int*   ei   = (const int*)d_in[1];
    const int*   qsrc = (const int*)d_in[2];
    const int*   qdst = (const int*)d_in[3];
    const float* Wl1  = (const float*)d_in[4];
    const float* bl1  = (const float*)d_in[5];
    const float* Wr1  = (const float*)d_in[6];
    const float* Wl2  = (const float*)d_in[7];
    const float* bl2  = (const float*)d_in[8];
    const float* Wr2  = (const float*)d_in[9];
    float* out = (float*)d_out;

    const int N = in_sizes[0] / 128;  // IN_CH = 128
    const int E = in_sizes[1] / 2;
    const int Q = in_sizes[2];

    const int* esrc = ei;
    const int* edst = ei + E;

    float* A = (float*)d_ws;              // N x 64 : p1, then p2
    float* B = A + (size_t)N * HID;       // N x 64 : q1, then h (in place)
    float* C = B + (size_t)N * HID;       // N x 64 : q2, then z (in place)
    int* deg    = (int*)(C + (size_t)N * HID);
    int* offs   = deg + N;
    int* bsums  = offs + N;               // up to 256 block sums
    int* sorted = bsums + 256;            // E ints
    int* rank   = (int*)A;                // aliases A (dead until gemm1)

    const int gE = (E + 255) / 256;
    const int nblk = (N + 1023) / 1024;   // <= 256
    const int gN = (N + 255) / 256;
    const int gG = (N + 127) / 128;
    const int gA = (N + 3) / 4;
    const int gQ = (Q + 3) / 4;

    hipMemsetAsync(deg, 0, sizeof(int) * (size_t)N, stream);
    k_hist<<<gE, 256, 0, stream>>>(edst, deg, rank, E);
    k_scan1<<<nblk, 256, 0, stream>>>(deg, offs, bsums, N);
    k_scan2<<<1, 256, 0, stream>>>(bsums, nblk);
    k_scan3<<<gN, 256, 0, stream>>>(offs, bsums, N);
    k_scatter<<<gE, 256, 0, stream>>>(esrc, edst, offs, rank, sorted, E);

    gemm_dual<128><<<gG, 256, 0, stream>>>(x, Wl1, Wr1, A, B, N);
    k_agg<<<gA, 256, 0, stream>>>(A, B, bl1, offs, deg, sorted, B, N);

    gemm_dual<64><<<gG, 256, 0, stream>>>(B, Wl2, Wr2, A, C, N);
    k_agg<<<gA, 256, 0, stream>>>(A, C, bl2, offs, deg, sorted, C, N);

    k_query<<<gQ, 256, 0, stream>>>(C, qsrc, qdst, out, Q);
}

// Round 4
// 450.879 us; speedup vs baseline: 1.2127x; 1.2127x over previous
//
#include <hip/hip_runtime.h>
#include <math.h>

// ---------------------------------------------------------------------------
// GNN link predictor: 2-layer GraphSAGE (mean agg) + dot-product + sigmoid.
// Restructurings:
//  - transform-then-aggregate (mean is linear) -> aggregate in 64-dim space
//  - CSR-by-dst built per call; scatter is ATOMIC-FREE (rank = histogram
//    atomic return value)
//  - wave-per-node pull aggregation (lane = channel, coalesced 256B rows)
//  - GEMM: K chunked to 64 (35.8KB LDS -> 4 blocks/CU), skewed LDS layout
//    phys(c)=c+4*(c>>5) -> W reads/writes 2-way (free; was 4-way, 3.1e7
//    conflict cycles in R2). R4: tile back to 4x8/thread — R3's 8x8 tile
//    spilled (VGPR capped 128 by launch_bounds(256,4): WRITE 50->99MB,
//    VALUBusy 31->18%). 4x8 = ~95 VGPR, fits.
// ---------------------------------------------------------------------------

#define HID 64
#define WSTRIDE 140  // 64 rows x 140 floats = 35,840 B LDS; rows 16B-aligned

// ---------------- CSR build ----------------

__global__ __launch_bounds__(256)
void k_hist(const int* __restrict__ edst, int* __restrict__ deg,
            int* __restrict__ rank, int E) {
    int e = blockIdx.x * 256 + threadIdx.x;
    if (e < E) rank[e] = atomicAdd(&deg[edst[e]], 1);
}

__global__ __launch_bounds__(256)
void k_scan1(const int* __restrict__ deg, int* __restrict__ offs,
             int* __restrict__ bsums, int n) {
    __shared__ int lds[256];
    int t = threadIdx.x;
    int base = blockIdx.x * 1024 + t * 4;
    int v0 = 0, v1 = 0, v2 = 0, v3 = 0;
    if (base + 0 < n) v0 = deg[base + 0];
    if (base + 1 < n) v1 = deg[base + 1];
    if (base + 2 < n) v2 = deg[base + 2];
    if (base + 3 < n) v3 = deg[base + 3];
    int ts = v0 + v1 + v2 + v3;
    lds[t] = ts;
    __syncthreads();
    for (int off = 1; off < 256; off <<= 1) {
        int x = (t >= off) ? lds[t - off] : 0;
        __syncthreads();
        lds[t] += x;
        __syncthreads();
    }
    int excl = lds[t] - ts;
    if (base + 0 < n) offs[base + 0] = excl;
    if (base + 1 < n) offs[base + 1] = excl + v0;
    if (base + 2 < n) offs[base + 2] = excl + v0 + v1;
    if (base + 3 < n) offs[base + 3] = excl + v0 + v1 + v2;
    if (t == 255) bsums[blockIdx.x] = lds[255];
}

__global__ __launch_bounds__(256)
void k_scan2(int* __restrict__ bsums, int nb) {
    __shared__ int lds[256];
    int t = threadIdx.x;
    int v = (t < nb) ? bsums[t] : 0;
    lds[t] = v;
    __syncthreads();
    for (int off = 1; off < 256; off <<= 1) {
        int x = (t >= off) ? lds[t - off] : 0;
        __syncthreads();
        lds[t] += x;
        __syncthreads();
    }
    if (t < nb) bsums[t] = lds[t] - v;
}

__global__ __launch_bounds__(256)
void k_scan3(int* __restrict__ offs, const int* __restrict__ bsums, int n) {
    int i = blockIdx.x * 256 + threadIdx.x;
    if (i < n) offs[i] += bsums[i >> 10];
}

__global__ __launch_bounds__(256)
void k_scatter(const int* __restrict__ esrc, const int* __restrict__ edst,
               const int* __restrict__ offs, const int* __restrict__ rank,
               int* __restrict__ sorted, int E) {
    int e = blockIdx.x * 256 + threadIdx.x;
    if (e < E) {
        int d = edst[e];
        sorted[offs[d] + rank[e]] = esrc[e];
    }
}

// ---------------- dual GEMM: P = X@Wl^T, Q = X@Wr^T (both 64 x K) ----------------
// 256 thr, 64 rows/block, thread = 4 rows x 8 cols. [Wl|Wr]^T staged in LDS
// with skew phys(c) = c + 4*(c>>5); K chunked by 64 -> 35.8 KB -> 4 blocks/CU.

__device__ __forceinline__ float f4get(const float4& v, int k) {
    return k == 0 ? v.x : k == 1 ? v.y : k == 2 ? v.z : v.w;
}

template <int K>
__global__ __launch_bounds__(256, 4)
void gemm_dual(const float* __restrict__ X, const float* __restrict__ Wl,
               const float* __restrict__ Wr, float* __restrict__ P,
               float* __restrict__ Qo, int N) {
    __shared__ float sW[64 * WSTRIDE];
    const int t = threadIdx.x;
    const int og = t & 15;   // 8-col group
    const int rg = t >> 4;   // 16 groups x 4 rows = 64 rows
    const int rbase = blockIdx.x * 64 + rg * 4;
    const int cskew = og * 8 + ((og >> 2) << 2);  // phys(og*8)

    int rowoff[4];
    bool ok[4];
#pragma unroll
    for (int i = 0; i < 4; ++i) {
        int r = rbase + i;
        ok[i] = (r < N);
        rowoff[i] = (ok[i] ? r : 0) * K;
    }

    float acc[4][8];
#pragma unroll
    for (int i = 0; i < 4; ++i)
#pragma unroll
        for (int j = 0; j < 8; ++j) acc[i][j] = 0.f;

    for (int k0 = 0; k0 < K; k0 += 64) {
        if (k0) __syncthreads();
        // stage 128 cols x 64 k of [Wl|Wr]^T. task tau: c_lo=tau&31 (bank
        // spread), k4=(tau>>5)&15 (float4 along k), c_hi=tau>>9 (wave-uniform).
#pragma unroll
        for (int m = 0; m < 8; ++m) {
            int tau = t + 256 * m;
            int c = (tau & 31) + ((tau >> 9) << 5);
            int k4 = (tau >> 5) & 15;
            const float* gsrc = (c < 64) ? (Wl + c * K + k0 + (k4 << 2))
                                         : (Wr + (c - 64) * K + k0 + (k4 << 2));
            float4 w = *(const float4*)gsrc;
            int base = (k4 << 2) * WSTRIDE + c + ((c >> 5) << 2);
            sW[base] = w.x;
            sW[base + WSTRIDE] = w.y;
            sW[base + 2 * WSTRIDE] = w.z;
            sW[base + 3 * WSTRIDE] = w.w;
        }
        __syncthreads();

        for (int kk4 = 0; kk4 < 64; kk4 += 4) {
            float4 xr[4];
#pragma unroll
            for (int i = 0; i < 4; ++i)
                xr[i] = *(const float4*)(X + (size_t)rowoff[i] + k0 + kk4);
            float4 w0[4], w1[4];
#pragma unroll
            for (int kk = 0; kk < 4; ++kk) {
                const float* wr_ = &sW[(kk4 + kk) * WSTRIDE + cskew];
                w0[kk] = *(const float4*)wr_;
                w1[kk] = *(const float4*)(wr_ + 4);
            }
#pragma unroll
            for (int kk = 0; kk < 4; ++kk) {
#pragma unroll
                for (int i = 0; i < 4; ++i) {
                    float xs = f4get(xr[i], kk);
                    acc[i][0] = fmaf(xs, w0[kk].x, acc[i][0]);
                    acc[i][1] = fmaf(xs, w0[kk].y, acc[i][1]);
                    acc[i][2] = fmaf(xs, w0[kk].z, acc[i][2]);
                    acc[i][3] = fmaf(xs, w0[kk].w, acc[i][3]);
                    acc[i][4] = fmaf(xs, w1[kk].x, acc[i][4]);
                    acc[i][5] = fmaf(xs, w1[kk].y, acc[i][5]);
                    acc[i][6] = fmaf(xs, w1[kk].z, acc[i][6]);
                    acc[i][7] = fmaf(xs, w1[kk].w, acc[i][7]);
                }
            }
        }
    }

    float* dstp = (og < 8) ? P : Qo;
    const int cb = (og < 8) ? og * 8 : og * 8 - 64;
#pragma unroll
    for (int i = 0; i < 4; ++i) {
        if (ok[i]) {
            float* p = dstp + (size_t)(rbase + i) * HID + cb;
            *(float4*)p = make_float4(acc[i][0], acc[i][1], acc[i][2], acc[i][3]);
            *(float4*)(p + 4) = make_float4(acc[i][4], acc[i][5], acc[i][6], acc[i][7]);
        }
    }
}

// ---------------- aggregation: H = relu(mean_{s in N(n)} P[s] + bias + Qin[n]) ----

__global__ __launch_bounds__(256)
void k_agg(const float* __restrict__ P, const float* Qin,
           const float* __restrict__ bias, const int* __restrict__ offs,
           const int* __restrict__ deg, const int* __restrict__ sorted,
           float* H, int N) {
    int wid = blockIdx.x * 4 + (threadIdx.x >> 6);
    int lane = threadIdx.x & 63;
    if (wid >= N) return;
    int off = __builtin_amdgcn_readfirstlane(offs[wid]);
    int c = __builtin_amdgcn_readfirstlane(deg[wid]);
    float acc = 0.f;
    int i = 0;
    for (; i + 3 < c; i += 4) {
        int s0 = sorted[off + i];
        int s1 = sorted[off + i + 1];
        int s2 = sorted[off + i + 2];
        int s3 = sorted[off + i + 3];
        float a0 = P[(size_t)s0 * HID + lane];
        float a1 = P[(size_t)s1 * HID + lane];
        float a2 = P[(size_t)s2 * HID + lane];
        float a3 = P[(size_t)s3 * HID + lane];
        acc += (a0 + a1) + (a2 + a3);
    }
    for (; i < c; ++i) acc += P[(size_t)sorted[off + i] * HID + lane];
    float inv = 1.0f / (float)(c > 0 ? c : 1);
    float v = acc * inv + bias[lane] + Qin[(size_t)wid * HID + lane];
    H[(size_t)wid * HID + lane] = v > 0.f ? v : 0.f;
}

// ---------------- query ----------------

__global__ __launch_bounds__(256)
void k_query(const float* __restrict__ Z, const int* __restrict__ src,
             const int* __restrict__ dst, float* __restrict__ out, int Q) {
    int q = blockIdx.x * 4 + (threadIdx.x >> 6);
    int lane = threadIdx.x & 63;
    if (q >= Q) return;
    int s = __builtin_amdgcn_readfirstlane(src[q]);
    int d = __builtin_amdgcn_readfirstlane(dst[q]);
    float v = Z[(size_t)s * HID + lane] * Z[(size_t)d * HID + lane];
#pragma unroll
    for (int m = 32; m > 0; m >>= 1) v += __shfl_xor(v, m, 64);
    if (lane == 0) out[q] = 1.0f / (1.0f + __expf(-v));
}

// ---------------- launch ----------------

extern "C" void kernel_launch(void* const* d_in, const int* in_sizes, int n_in,
                              void* d_out, int out_size, void* d_ws, size_t ws_size,
                              hipStream_t stream) {
    const float* x    = (const float*)d_in[0];
    const int*   ei   = (const int*)d_in[1];
    const int*   qsrc = (const int*)d_in[2];
    const int*   qdst = (const int*)d_in[3];
    const float* Wl1  = (const float*)d_in[4];
    const float* bl1  = (const float*)d_in[5];
    const float* Wr1  = (const float*)d_in[6];
    const float* Wl2  = (const float*)d_in[7];
    const float* bl2  = (const float*)d_in[8];
    const float* Wr2  = (const float*)d_in[9];
    float* out = (float*)d_out;

    const int N = in_sizes[0] / 128;  // IN_CH = 128
    const int E = in_sizes[1] / 2;
    const int Q = in_sizes[2];

    const int* esrc = ei;
    const int* edst = ei + E;

    float* A = (float*)d_ws;              // N x 64 : p1, then p2
    float* B = A + (size_t)N * HID;       // N x 64 : q1, then h (in place)
    float* C = B + (size_t)N * HID;       // N x 64 : q2, then z (in place)
    int* deg    = (int*)(C + (size_t)N * HID);
    int* offs   = deg + N;
    int* bsums  = offs + N;               // up to 256 block sums
    int* sorted = bsums + 256;            // E ints
    int* rank   = (int*)A;                // aliases A (dead until gemm1)

    const int gE = (E + 255) / 256;
    const int nblk = (N + 1023) / 1024;   // <= 256
    const int gN = (N + 255) / 256;
    const int gG = (N + 63) / 64;
    const int gA = (N + 3) / 4;
    const int gQ = (Q + 3) / 4;

    hipMemsetAsync(deg, 0, sizeof(int) * (size_t)N, stream);
    k_hist<<<gE, 256, 0, stream>>>(edst, deg, rank, E);
    k_scan1<<<nblk, 256, 0, stream>>>(deg, offs, bsums, N);
    k_scan2<<<1, 256, 0, stream>>>(bsums, nblk);
    k_scan3<<<gN, 256, 0, stream>>>(offs, bsums, N);
    k_scatter<<<gE, 256, 0, stream>>>(esrc, edst, offs, rank, sorted, E);

    gemm_dual<128><<<gG, 256, 0, stream>>>(x, Wl1, Wr1, A, B, N);
    k_agg<<<gA, 256, 0, stream>>>(A, B, bl1, offs, deg, sorted, B, N);

    gemm_dual<64><<<gG, 256, 0, stream>>>(B, Wl2, Wr2, A, C, N);
    k_agg<<<gA, 256, 0, stream>>>(A, C, bl2, offs, deg, sorted, C, N);

    k_query<<<gQ, 256, 0, stream>>>(C, qsrc, qdst, out, Q);
}

// Round 5
// 424.832 us; speedup vs baseline: 1.2870x; 1.0613x over previous
//
#include <hip/hip_runtime.h>
#include <math.h>

// ---------------------------------------------------------------------------
// GNN link predictor: 2-layer GraphSAGE (mean agg) + dot-product + sigmoid.
// Restructurings:
//  - transform-then-aggregate (mean is linear) -> aggregate in 64-dim space
//  - CSR-by-dst built per call; scatter is ATOMIC-FREE (rank = histogram
//    atomic return value)
//  - wave-per-node pull aggregation (lane = channel, coalesced rows)
//  - GEMM: K chunked to 64 (35.8KB LDS), skew phys(c)=c+4*(c>>5) -> LDS
//    reads/writes 2-way (free). R5: 8x8/thread tile with launch_bounds(256,2)
//    (R3's spill was the 128-VGPR cap from (256,4), not the tile itself) —
//    doubles FMA per LDS byte, LDS pipe no longer oversubscribed.
//  - R5: messages P and embeddings Z stored bf16 (fp32 accumulate, single
//    rounding) -> gather traffic halved in k_agg x2 and k_query.
// ---------------------------------------------------------------------------

#define HID 64
#define WSTRIDE 140  // 64 rows x 140 floats = 35,840 B LDS; rows 16B-aligned

__device__ __forceinline__ unsigned short f2bf(float f) {
    union { float f; unsigned u; } v; v.f = f;
    unsigned r = v.u + 0x7FFF + ((v.u >> 16) & 1);  // round-to-nearest-even
    return (unsigned short)(r >> 16);
}
__device__ __forceinline__ float bf2f(unsigned short u) {
    union { unsigned u; float f; } v; v.u = ((unsigned)u) << 16;
    return v.f;
}

// ---------------- CSR build ----------------

__global__ __launch_bounds__(256)
void k_hist(const int* __restrict__ edst, int* __restrict__ deg,
            int* __restrict__ rank, int E) {
    int e = blockIdx.x * 256 + threadIdx.x;
    if (e < E) rank[e] = atomicAdd(&deg[edst[e]], 1);
}

__global__ __launch_bounds__(256)
void k_scan1(const int* __restrict__ deg, int* __restrict__ offs,
             int* __restrict__ bsums, int n) {
    __shared__ int lds[256];
    int t = threadIdx.x;
    int base = blockIdx.x * 1024 + t * 4;
    int v0 = 0, v1 = 0, v2 = 0, v3 = 0;
    if (base + 0 < n) v0 = deg[base + 0];
    if (base + 1 < n) v1 = deg[base + 1];
    if (base + 2 < n) v2 = deg[base + 2];
    if (base + 3 < n) v3 = deg[base + 3];
    int ts = v0 + v1 + v2 + v3;
    lds[t] = ts;
    __syncthreads();
    for (int off = 1; off < 256; off <<= 1) {
        int x = (t >= off) ? lds[t - off] : 0;
        __syncthreads();
        lds[t] += x;
        __syncthreads();
    }
    int excl = lds[t] - ts;
    if (base + 0 < n) offs[base + 0] = excl;
    if (base + 1 < n) offs[base + 1] = excl + v0;
    if (base + 2 < n) offs[base + 2] = excl + v0 + v1;
    if (base + 3 < n) offs[base + 3] = excl + v0 + v1 + v2;
    if (t == 255) bsums[blockIdx.x] = lds[255];
}

__global__ __launch_bounds__(256)
void k_scan2(int* __restrict__ bsums, int nb) {
    __shared__ int lds[256];
    int t = threadIdx.x;
    int v = (t < nb) ? bsums[t] : 0;
    lds[t] = v;
    __syncthreads();
    for (int off = 1; off < 256; off <<= 1) {
        int x = (t >= off) ? lds[t - off] : 0;
        __syncthreads();
        lds[t] += x;
        __syncthreads();
    }
    if (t < nb) bsums[t] = lds[t] - v;
}

__global__ __launch_bounds__(256)
void k_scan3(int* __restrict__ offs, const int* __restrict__ bsums, int n) {
    int i = blockIdx.x * 256 + threadIdx.x;
    if (i < n) offs[i] += bsums[i >> 10];
}

__global__ __launch_bounds__(256)
void k_scatter(const int* __restrict__ esrc, const int* __restrict__ edst,
               const int* __restrict__ offs, const int* __restrict__ rank,
               int* __restrict__ sorted, int E) {
    int e = blockIdx.x * 256 + threadIdx.x;
    if (e < E) {
        int d = edst[e];
        sorted[offs[d] + rank[e]] = esrc[e];
    }
}

// ---------------- dual GEMM: P(bf16) = X@Wl^T, Q(f32) = X@Wr^T ----------------
// 256 thr, 128 rows/block, thread = 8 rows x 8 cols. [Wl|Wr]^T staged in LDS
// with skew phys(c)=c+4*(c>>5); K chunked by 64.

__device__ __forceinline__ float f4get(const float4& v, int k) {
    return k == 0 ? v.x : k == 1 ? v.y : k == 2 ? v.z : v.w;
}

template <int K>
__global__ __launch_bounds__(256, 2)
void gemm_dual(const float* __restrict__ X, const float* __restrict__ Wl,
               const float* __restrict__ Wr, unsigned short* __restrict__ Pb,
               float* __restrict__ Qo, int N) {
    __shared__ float sW[64 * WSTRIDE];
    const int t = threadIdx.x;
    const int og = t & 15;   // 8-col group
    const int rg = t >> 4;   // 16 groups x 8 rows = 128 rows
    const int rbase = blockIdx.x * 128 + rg * 8;
    const int cskew = og * 8 + ((og >> 2) << 2);  // phys(og*8)

    int rowoff[8];
    bool ok[8];
#pragma unroll
    for (int i = 0; i < 8; ++i) {
        int r = rbase + i;
        ok[i] = (r < N);
        rowoff[i] = (ok[i] ? r : 0) * K;
    }

    float acc[8][8];
#pragma unroll
    for (int i = 0; i < 8; ++i)
#pragma unroll
        for (int j = 0; j < 8; ++j) acc[i][j] = 0.f;

    for (int k0 = 0; k0 < K; k0 += 64) {
        if (k0) __syncthreads();
        // stage 128 cols x 64 k of [Wl|Wr]^T; LDS writes 2-way (free)
#pragma unroll
        for (int m = 0; m < 8; ++m) {
            int tau = t + 256 * m;
            int c = (tau & 31) + ((tau >> 9) << 5);
            int k4 = (tau >> 5) & 15;
            const float* gsrc = (c < 64) ? (Wl + c * K + k0 + (k4 << 2))
                                         : (Wr + (c - 64) * K + k0 + (k4 << 2));
            float4 w = *(const float4*)gsrc;
            int base = (k4 << 2) * WSTRIDE + c + ((c >> 5) << 2);
            sW[base] = w.x;
            sW[base + WSTRIDE] = w.y;
            sW[base + 2 * WSTRIDE] = w.z;
            sW[base + 3 * WSTRIDE] = w.w;
        }
        __syncthreads();

        for (int kk4 = 0; kk4 < 64; kk4 += 4) {
            float4 xr[8];
#pragma unroll
            for (int i = 0; i < 8; ++i)
                xr[i] = *(const float4*)(X + (size_t)rowoff[i] + k0 + kk4);
            float4 w0[4], w1[4];
#pragma unroll
            for (int kk = 0; kk < 4; ++kk) {
                const float* wr_ = &sW[(kk4 + kk) * WSTRIDE + cskew];
                w0[kk] = *(const float4*)wr_;
                w1[kk] = *(const float4*)(wr_ + 4);
            }
#pragma unroll
            for (int kk = 0; kk < 4; ++kk) {
#pragma unroll
                for (int i = 0; i < 8; ++i) {
                    float xs = f4get(xr[i], kk);
                    acc[i][0] = fmaf(xs, w0[kk].x, acc[i][0]);
                    acc[i][1] = fmaf(xs, w0[kk].y, acc[i][1]);
                    acc[i][2] = fmaf(xs, w0[kk].z, acc[i][2]);
                    acc[i][3] = fmaf(xs, w0[kk].w, acc[i][3]);
                    acc[i][4] = fmaf(xs, w1[kk].x, acc[i][4]);
                    acc[i][5] = fmaf(xs, w1[kk].y, acc[i][5]);
                    acc[i][6] = fmaf(xs, w1[kk].z, acc[i][6]);
                    acc[i][7] = fmaf(xs, w1[kk].w, acc[i][7]);
                }
            }
        }
    }

    if (og < 8) {
        // message path -> bf16 rows (gathered randomly by k_agg)
        const int cb = og * 8;
#pragma unroll
        for (int i = 0; i < 8; ++i) {
            if (ok[i]) {
                uint4 pk;
                pk.x = (unsigned)f2bf(acc[i][0]) | ((unsigned)f2bf(acc[i][1]) << 16);
                pk.y = (unsigned)f2bf(acc[i][2]) | ((unsigned)f2bf(acc[i][3]) << 16);
                pk.z = (unsigned)f2bf(acc[i][4]) | ((unsigned)f2bf(acc[i][5]) << 16);
                pk.w = (unsigned)f2bf(acc[i][6]) | ((unsigned)f2bf(acc[i][7]) << 16);
                *(uint4*)(Pb + (size_t)(rbase + i) * HID + cb) = pk;
            }
        }
    } else {
        // root path -> fp32 (read once, coalesced)
        const int cb = og * 8 - 64;
#pragma unroll
        for (int i = 0; i < 8; ++i) {
            if (ok[i]) {
                float* p = Qo + (size_t)(rbase + i) * HID + cb;
                *(float4*)p = make_float4(acc[i][0], acc[i][1], acc[i][2], acc[i][3]);
                *(float4*)(p + 4) = make_float4(acc[i][4], acc[i][5], acc[i][6], acc[i][7]);
            }
        }
    }
}

// ------- aggregation: H = relu(mean_{s in N(n)} P[s] + bias + Qin[n]) -------
// one 64-lane wave per node, lane = channel. P is bf16; accumulate fp32.
// OUT_BF16: layer2 writes bf16 embeddings for the query gather.

template <bool OUT_BF16>
__global__ __launch_bounds__(256)
void k_agg(const unsigned short* __restrict__ P, const float* __restrict__ Qin,
           const float* __restrict__ bias, const int* __restrict__ offs,
           const int* __restrict__ deg, const int* __restrict__ sorted,
           void* __restrict__ Hout, int N) {
    int wid = blockIdx.x * 4 + (threadIdx.x >> 6);
    int lane = threadIdx.x & 63;
    if (wid >= N) return;
    int off = __builtin_amdgcn_readfirstlane(offs[wid]);
    int c = __builtin_amdgcn_readfirstlane(deg[wid]);
    float acc = 0.f;
    int i = 0;
    for (; i + 3 < c; i += 4) {
        int s0 = sorted[off + i];
        int s1 = sorted[off + i + 1];
        int s2 = sorted[off + i + 2];
        int s3 = sorted[off + i + 3];
        float a0 = bf2f(P[(size_t)s0 * HID + lane]);
        float a1 = bf2f(P[(size_t)s1 * HID + lane]);
        float a2 = bf2f(P[(size_t)s2 * HID + lane]);
        float a3 = bf2f(P[(size_t)s3 * HID + lane]);
        acc += (a0 + a1) + (a2 + a3);
    }
    for (; i < c; ++i) acc += bf2f(P[(size_t)sorted[off + i] * HID + lane]);
    float inv = 1.0f / (float)(c > 0 ? c : 1);
    float v = acc * inv + bias[lane] + Qin[(size_t)wid * HID + lane];
    v = v > 0.f ? v : 0.f;
    if (OUT_BF16)
        ((unsigned short*)Hout)[(size_t)wid * HID + lane] = f2bf(v);
    else
        ((float*)Hout)[(size_t)wid * HID + lane] = v;
}

// ---------------- query: out[q] = sigmoid(sum_c Z[s][c]*Z[d][c]) ----------------

__global__ __launch_bounds__(256)
void k_query(const unsigned short* __restrict__ Z, const int* __restrict__ src,
             const int* __restrict__ dst, float* __restrict__ out, int Q) {
    int q = blockIdx.x * 4 + (threadIdx.x >> 6);
    int lane = threadIdx.x & 63;
    if (q >= Q) return;
    int s = __builtin_amdgcn_readfirstlane(src[q]);
    int d = __builtin_amdgcn_readfirstlane(dst[q]);
    float v = bf2f(Z[(size_t)s * HID + lane]) * bf2f(Z[(size_t)d * HID + lane]);
#pragma unroll
    for (int m = 32; m > 0; m >>= 1) v += __shfl_xor(v, m, 64);
    if (lane == 0) out[q] = 1.0f / (1.0f + __expf(-v));
}

// ---------------- launch ----------------

extern "C" void kernel_launch(void* const* d_in, const int* in_sizes, int n_in,
                              void* d_out, int out_size, void* d_ws, size_t ws_size,
                              hipStream_t stream) {
    const float* x    = (const float*)d_in[0];
    const int*   ei   = (const int*)d_in[1];
    const int*   qsrc = (const int*)d_in[2];
    const int*   qdst = (const int*)d_in[3];
    const float* Wl1  = (const float*)d_in[4];
    const float* bl1  = (const float*)d_in[5];
    const float* Wr1  = (const float*)d_in[6];
    const float* Wl2  = (const float*)d_in[7];
    const float* bl2  = (const float*)d_in[8];
    const float* Wr2  = (const float*)d_in[9];
    float* out = (float*)d_out;

    const int N = in_sizes[0] / 128;  // IN_CH = 128
    const int E = in_sizes[1] / 2;
    const int Q = in_sizes[2];

    const int* esrc = ei;
    const int* edst = ei + E;

    // workspace layout
    float* B  = (float*)d_ws;                    // N x 64 f32 : q1, then h (in place)
    float* Qc = B + (size_t)N * HID;             // N x 64 f32 : q2
    unsigned short* Pb = (unsigned short*)(Qc + (size_t)N * HID);  // N x 64 bf16 msgs
    unsigned short* Zb = Pb + (size_t)N * HID;   // N x 64 bf16 : z
    int* deg    = (int*)(Zb + (size_t)N * HID);
    int* offs   = deg + N;
    int* bsums  = offs + N;                      // up to 256 block sums
    int* sorted = bsums + 256;                   // E ints
    int* rank   = (int*)Pb;                      // alias: Pb dead until gemm1

    const int gE = (E + 255) / 256;
    const int nblk = (N + 1023) / 1024;          // <= 256
    const int gN = (N + 255) / 256;
    const int gG = (N + 127) / 128;
    const int gA = (N + 3) / 4;
    const int gQ = (Q + 3) / 4;

    hipMemsetAsync(deg, 0, sizeof(int) * (size_t)N, stream);
    k_hist<<<gE, 256, 0, stream>>>(edst, deg, rank, E);
    k_scan1<<<nblk, 256, 0, stream>>>(deg, offs, bsums, N);
    k_scan2<<<1, 256, 0, stream>>>(bsums, nblk);
    k_scan3<<<gN, 256, 0, stream>>>(offs, bsums, N);
    k_scatter<<<gE, 256, 0, stream>>>(esrc, edst, offs, rank, sorted, E);

    // layer 1: Pb = bf16(x@Wl1^T), B = x@Wr1^T; h = relu(mean+b+B) -> B (f32)
    gemm_dual<128><<<gG, 256, 0, stream>>>(x, Wl1, Wr1, Pb, B, N);
    k_agg<false><<<gA, 256, 0, stream>>>(Pb, B, bl1, offs, deg, sorted, B, N);

    // layer 2: Pb = bf16(h@Wl2^T), Qc = h@Wr2^T; z = relu(mean+b+Qc) -> Zb (bf16)
    gemm_dual<64><<<gG, 256, 0, stream>>>(B, Wl2, Wr2, Pb, Qc, N);
    k_agg<true><<<gA, 256, 0, stream>>>(Pb, Qc, bl2, offs, deg, sorted, Zb, N);

    // queries
    k_query<<<gQ, 256, 0, stream>>>(Zb, qsrc, qdst, out, Q);
}

// Round 6
// 346.541 us; speedup vs baseline: 1.5778x; 1.2259x over previous
//
#include <hip/hip_runtime.h>
#include <hip/hip_bf16.h>
#include <math.h>

// ---------------------------------------------------------------------------
// GNN link predictor: 2-layer GraphSAGE (mean agg) + dot-product + sigmoid.
//  - transform-then-aggregate (mean is linear) -> aggregate in 64-dim space
//  - CSR-by-dst built per call; scatter ATOMIC-FREE (rank = hist atomic ret)
//  - R6: GEMMs on MFMA (16x16x32 bf16, fp32 accum). fp32-FMA path was boxed
//    at 44 TF / 74us; MFMA makes both gemms memory-bound (~20/12us).
//    Layouts per HW-verified m89/m91: A/B frag = 8 contig k at row lane&15,
//    k-off (lane>>4)*8; C/D col=lane&15, row=(lane>>4)*4+reg.
//  - R6: k_agg/k_query widened to 2 nodes/wave (32 lanes x bf16x2-uint loads)
//    -> half the gather instructions, 2x bytes/load in flight.
// ---------------------------------------------------------------------------

#define HID 64

typedef __attribute__((ext_vector_type(8))) short short8;   // 8 bf16 (4 VGPR)
typedef __attribute__((ext_vector_type(4))) float floatx4;  // MFMA acc

__device__ __forceinline__ unsigned short f2bf(float f) {
    union { float f; unsigned u; } v; v.f = f;
    unsigned r = v.u + 0x7FFF + ((v.u >> 16) & 1);  // round-to-nearest-even
    return (unsigned short)(r >> 16);
}
__device__ __forceinline__ float bf2f(unsigned short u) {
    union { unsigned u; float f; } v; v.u = ((unsigned)u) << 16;
    return v.f;
}
__device__ __forceinline__ unsigned pack_bf2(float a, float b) {
    union { __hip_bfloat162 h; unsigned u; } cv;
    cv.h = __float22bfloat162_rn(make_float2(a, b));  // v_cvt_pk_bf16_f32
    return cv.u;
}

// ---------------- CSR build ----------------

__global__ __launch_bounds__(256)
void k_hist(const int* __restrict__ edst, int* __restrict__ deg,
            int* __restrict__ rank, int E) {
    int e = blockIdx.x * 256 + threadIdx.x;
    if (e < E) rank[e] = atomicAdd(&deg[edst[e]], 1);
}

__global__ __launch_bounds__(256)
void k_scan1(const int* __restrict__ deg, int* __restrict__ offs,
             int* __restrict__ bsums, int n) {
    __shared__ int lds[256];
    int t = threadIdx.x;
    int base = blockIdx.x * 1024 + t * 4;
    int v0 = 0, v1 = 0, v2 = 0, v3 = 0;
    if (base + 0 < n) v0 = deg[base + 0];
    if (base + 1 < n) v1 = deg[base + 1];
    if (base + 2 < n) v2 = deg[base + 2];
    if (base + 3 < n) v3 = deg[base + 3];
    int ts = v0 + v1 + v2 + v3;
    lds[t] = ts;
    __syncthreads();
    for (int off = 1; off < 256; off <<= 1) {
        int x = (t >= off) ? lds[t - off] : 0;
        __syncthreads();
        lds[t] += x;
        __syncthreads();
    }
    int excl = lds[t] - ts;
    if (base + 0 < n) offs[base + 0] = excl;
    if (base + 1 < n) offs[base + 1] = excl + v0;
    if (base + 2 < n) offs[base + 2] = excl + v0 + v1;
    if (base + 3 < n) offs[base + 3] = excl + v0 + v1 + v2;
    if (t == 255) bsums[blockIdx.x] = lds[255];
}

__global__ __launch_bounds__(256)
void k_scan2(int* __restrict__ bsums, int nb) {
    __shared__ int lds[256];
    int t = threadIdx.x;
    int v = (t < nb) ? bsums[t] : 0;
    lds[t] = v;
    __syncthreads();
    for (int off = 1; off < 256; off <<= 1) {
        int x = (t >= off) ? lds[t - off] : 0;
        __syncthreads();
        lds[t] += x;
        __syncthreads();
    }
    if (t < nb) bsums[t] = lds[t] - v;
}

__global__ __launch_bounds__(256)
void k_scan3(int* __restrict__ offs, const int* __restrict__ bsums, int n) {
    int i = blockIdx.x * 256 + threadIdx.x;
    if (i < n) offs[i] += bsums[i >> 10];
}

__global__ __launch_bounds__(256)
void k_scatter(const int* __restrict__ esrc, const int* __restrict__ edst,
               const int* __restrict__ offs, const int* __restrict__ rank,
               int* __restrict__ sorted, int E) {
    int e = blockIdx.x * 256 + threadIdx.x;
    if (e < E) {
        int d = edst[e];
        sorted[offs[d] + rank[e]] = esrc[e];
    }
}

// ---------------- W cast: Wcb1 = bf16([Wl1;Wr1]) 128xK1, Wcb2 = bf16([Wl2;Wr2]) 128x64

__global__ __launch_bounds__(256)
void k_castw(const float* __restrict__ Wl1, const float* __restrict__ Wr1,
             const float* __restrict__ Wl2, const float* __restrict__ Wr2,
             unsigned short* __restrict__ Wcb1, unsigned short* __restrict__ Wcb2) {
    int i = blockIdx.x * 256 + threadIdx.x;
    if (i < 16384) {
        Wcb1[i] = f2bf(i < 8192 ? Wl1[i] : Wr1[i - 8192]);
    } else if (i < 24576) {
        int j = i - 16384;
        Wcb2[j] = f2bf(j < 4096 ? Wl2[j] : Wr2[j - 4096]);
    }
}

// ---------------- MFMA dual GEMM: [P|Q] = A @ [Wl;Wr]^T ----------------
// Wave computes 16 rows x 64 cols (half=0 -> P bf16, half=1 -> Q f32).
// B-frags (the W half) held in registers across a grid-stride row-tile loop.
// A is f32 (layer 1, cvt in-flight) or bf16 (layer 2).

template <int K, bool AF32>
__global__ __launch_bounds__(256, 2)
void gemm_mfma(const void* __restrict__ Xv, const unsigned short* __restrict__ Wcb,
               unsigned short* __restrict__ Pb, float* __restrict__ Qc, int N) {
    const int lane = threadIdx.x & 63;
    const int m = lane & 15;        // row (A) / col (B) within tile
    const int q = lane >> 4;        // k-quad
    const int gw = blockIdx.x * 4 + (threadIdx.x >> 6);
    const int half = gw & 1;        // 0 -> P (cols 0..63), 1 -> Q (cols 64..127)
    constexpr int KB = K / 32;

    short8 bf[KB][4];
#pragma unroll
    for (int kb = 0; kb < KB; ++kb)
#pragma unroll
        for (int ct = 0; ct < 4; ++ct) {
            int c = half * 64 + ct * 16 + m;
            bf[kb][ct] = *(const short8*)(Wcb + (size_t)c * K + kb * 32 + q * 8);
        }

    const int ntiles = (N + 15) >> 4;
    const int stride = gridDim.x * 2;  // waves per half
    for (int t = gw >> 1; t < ntiles; t += stride) {
        const int r0 = t << 4;
        int rr = r0 + m;
        if (rr >= N) rr = N - 1;
        floatx4 acc[4];
#pragma unroll
        for (int ct = 0; ct < 4; ++ct) acc[ct] = (floatx4){0.f, 0.f, 0.f, 0.f};

#pragma unroll
        for (int kb = 0; kb < KB; ++kb) {
            short8 a;
            if (AF32) {
                const float* xp = (const float*)Xv + (size_t)rr * K + kb * 32 + q * 8;
                float4 x0 = *(const float4*)xp;
                float4 x1 = *(const float4*)(xp + 4);
                union { unsigned u[4]; short8 s; } cv;
                cv.u[0] = pack_bf2(x0.x, x0.y);
                cv.u[1] = pack_bf2(x0.z, x0.w);
                cv.u[2] = pack_bf2(x1.x, x1.y);
                cv.u[3] = pack_bf2(x1.z, x1.w);
                a = cv.s;
            } else {
                a = *(const short8*)((const unsigned short*)Xv + (size_t)rr * K + kb * 32 + q * 8);
            }
#pragma unroll
            for (int ct = 0; ct < 4; ++ct)
                acc[ct] = __builtin_amdgcn_mfma_f32_16x16x32_bf16(a, bf[kb][ct], acc[ct], 0, 0, 0);
        }

        // C/D: col = ct*16 + m, row = r0 + q*4 + i
#pragma unroll
        for (int i = 0; i < 4; ++i) {
            int row = r0 + q * 4 + i;
            if (row < N) {
                if (half == 0) {
#pragma unroll
                    for (int ct = 0; ct < 4; ++ct)
                        Pb[(size_t)row * HID + ct * 16 + m] = f2bf(acc[ct][i]);
                } else {
#pragma unroll
                    for (int ct = 0; ct < 4; ++ct)
                        Qc[(size_t)row * HID + ct * 16 + m] = acc[ct][i];
                }
            }
        }
    }
}

// ------- aggregation: H = relu(mean_{s in N(n)} P[s] + bias + Qin[n]) -------
// 2 nodes per wave (32 lanes/node), lane = channel pair (bf16x2 uint loads).
// Output always bf16 (consumed by gemm2 A-path or k_query).

__global__ __launch_bounds__(256)
void k_agg(const unsigned* __restrict__ P32, const float2* __restrict__ Qin2,
           const float2* __restrict__ bias2, const int* __restrict__ offs,
           const int* __restrict__ deg, const int* __restrict__ sorted,
           unsigned* __restrict__ H32, int N) {
    int node = blockIdx.x * 8 + (threadIdx.x >> 5);
    int c32 = threadIdx.x & 31;
    if (node >= N) return;
    int off = offs[node];
    int c = deg[node];
    float a0 = 0.f, a1 = 0.f;
    int i = 0;
    for (; i + 3 < c; i += 4) {
        int s0 = sorted[off + i];
        int s1 = sorted[off + i + 1];
        int s2 = sorted[off + i + 2];
        int s3 = sorted[off + i + 3];
        unsigned u0 = P32[(size_t)s0 * 32 + c32];
        unsigned u1 = P32[(size_t)s1 * 32 + c32];
        unsigned u2 = P32[(size_t)s2 * 32 + c32];
        unsigned u3 = P32[(size_t)s3 * 32 + c32];
        a0 += (bf2f((unsigned short)u0) + bf2f((unsigned short)u1)) +
              (bf2f((unsigned short)u2) + bf2f((unsigned short)u3));
        a1 += (bf2f((unsigned short)(u0 >> 16)) + bf2f((unsigned short)(u1 >> 16))) +
              (bf2f((unsigned short)(u2 >> 16)) + bf2f((unsigned short)(u3 >> 16)));
    }
    for (; i < c; ++i) {
        unsigned u = P32[(size_t)sorted[off + i] * 32 + c32];
        a0 += bf2f((unsigned short)u);
        a1 += bf2f((unsigned short)(u >> 16));
    }
    float inv = 1.0f / (float)(c > 0 ? c : 1);
    float2 bv = bias2[c32];
    float2 qv = Qin2[(size_t)node * 32 + c32];
    float v0 = a0 * inv + bv.x + qv.x;
    float v1 = a1 * inv + bv.y + qv.y;
    v0 = v0 > 0.f ? v0 : 0.f;
    v1 = v1 > 0.f ? v1 : 0.f;
    H32[(size_t)node * 32 + c32] = (unsigned)f2bf(v0) | ((unsigned)f2bf(v1) << 16);
}

// ---------------- query: out[q] = sigmoid(sum_c Z[s][c]*Z[d][c]) ----------------
// 2 queries per wave (32 lanes each), uint bf16x2 loads.

__global__ __launch_bounds__(256)
void k_query(const unsigned* __restrict__ Z32, const int* __restrict__ src,
             const int* __restrict__ dst, float* __restrict__ out, int Q) {
    int qi = blockIdx.x * 8 + (threadIdx.x >> 5);
    int c32 = threadIdx.x & 31;
    if (qi >= Q) return;
    int s = src[qi];
    int d = dst[qi];
    unsigned us = Z32[(size_t)s * 32 + c32];
    unsigned ud = Z32[(size_t)d * 32 + c32];
    float v = bf2f((unsigned short)us) * bf2f((unsigned short)ud) +
              bf2f((unsigned short)(us >> 16)) * bf2f((unsigned short)(ud >> 16));
#pragma unroll
    for (int mres = 16; mres > 0; mres >>= 1) v += __shfl_xor(v, mres, 64);
    if (c32 == 0) out[qi] = 1.0f / (1.0f + __expf(-v));
}

// ---------------- launch ----------------

extern "C" void kernel_launch(void* const* d_in, const int* in_sizes, int n_in,
                              void* d_out, int out_size, void* d_ws, size_t ws_size,
                              hipStream_t stream) {
    const float* x    = (const float*)d_in[0];
    const int*   ei   = (const int*)d_in[1];
    const int*   qsrc = (const int*)d_in[2];
    const int*   qdst = (const int*)d_in[3];
    const float* Wl1  = (const float*)d_in[4];
    const float* bl1  = (const float*)d_in[5];
    const float* Wr1  = (const float*)d_in[6];
    const float* Wl2  = (const float*)d_in[7];
    const float* bl2  = (const float*)d_in[8];
    const float* Wr2  = (const float*)d_in[9];
    float* out = (float*)d_out;

    const int N = in_sizes[0] / 128;  // IN_CH = 128
    const int E = in_sizes[1] / 2;
    const int Q = in_sizes[2];

    const int* esrc = ei;
    const int* edst = ei + E;

    // workspace layout
    float*          Qc  = (float*)d_ws;                       // N x 64 f32 (root path, both layers)
    unsigned short* Pb  = (unsigned short*)(Qc + (size_t)N * HID);  // N x 64 bf16 messages
    unsigned short* Hb  = Pb + (size_t)N * HID;               // N x 64 bf16 h
    unsigned short* Zb  = Hb + (size_t)N * HID;               // N x 64 bf16 z
    int* deg    = (int*)(Zb + (size_t)N * HID);
    int* offs   = deg + N;
    int* bsums  = offs + N;                                   // up to 256
    int* sorted = bsums + 256;                                // E ints
    unsigned short* Wcb1 = (unsigned short*)(sorted + E);     // 128x128 bf16
    unsigned short* Wcb2 = Wcb1 + 16384;                      // 128x64 bf16
    int* rank = (int*)Pb;  // alias: Pb dead until gemm1, rank dead after scatter

    const int gE = (E + 255) / 256;
    const int nblk = (N + 1023) / 1024;  // <= 256
    const int gN = (N + 255) / 256;
    const int gG = 640;                  // grid-stride MFMA gemm
    const int gA = (N + 7) / 8;          // 2 nodes/wave, 4 waves/block
    const int gQ = (Q + 7) / 8;

    hipMemsetAsync(deg, 0, sizeof(int) * (size_t)N, stream);
    k_castw<<<96, 256, 0, stream>>>(Wl1, Wr1, Wl2, Wr2, Wcb1, Wcb2);
    k_hist<<<gE, 256, 0, stream>>>(edst, deg, rank, E);
    k_scan1<<<nblk, 256, 0, stream>>>(deg, offs, bsums, N);
    k_scan2<<<1, 256, 0, stream>>>(bsums, nblk);
    k_scan3<<<gN, 256, 0, stream>>>(offs, bsums, N);
    k_scatter<<<gE, 256, 0, stream>>>(esrc, edst, offs, rank, sorted, E);

    // layer 1: Pb = bf16(x@Wl1^T), Qc = x@Wr1^T; Hb = bf16(relu(mean+b+Qc))
    gemm_mfma<128, true><<<gG, 256, 0, stream>>>(x, Wcb1, Pb, Qc, N);
    k_agg<<<gA, 256, 0, stream>>>((const unsigned*)Pb, (const float2*)Qc,
                                  (const float2*)bl1, offs, deg, sorted,
                                  (unsigned*)Hb, N);

    // layer 2: Pb = bf16(Hb@Wl2^T), Qc = Hb@Wr2^T; Zb = bf16(relu(mean+b+Qc))
    gemm_mfma<64, false><<<gG, 256, 0, stream>>>(Hb, Wcb2, Pb, Qc, N);
    k_agg<<<gA, 256, 0, stream>>>((const unsigned*)Pb, (const float2*)Qc,
                                  (const float2*)bl2, offs, deg, sorted,
                                  (unsigned*)Zb, N);

    // queries
    k_query<<<gQ, 256, 0, stream>>>((const unsigned*)Zb, qsrc, qdst, out, Q);
}

// Round 7
// 324.299 us; speedup vs baseline: 1.6860x; 1.0686x over previous
//
#include <hip/hip_runtime.h>
#include <hip/hip_bf16.h>
#include <math.h>

// ---------------------------------------------------------------------------
// GNN link predictor: 2-layer GraphSAGE (mean agg) + dot-product + sigmoid.
//  - transform-then-aggregate (mean is linear) -> aggregate in 64-dim space
//  - CSR-by-dst built per call; scatter ATOMIC-FREE (rank = hist atomic ret)
//  - GEMMs on MFMA (16x16x32 bf16, fp32 accum), W-frags register-resident
//  - R7: histogram atomic counters padded to 1/64B-line (deg_s stride 16):
//    R6 showed k_hist 67us with WRITE 56MB = near-memory atomics serializing
//    ~256 deep per line. Counters strided -> per-line queue depth 16x lower.
//    deg_s aliases Qc (dead until gemm1). scan1 emits compact deg_c.
//  - R7: k_agg/k_query gathers widened to uint2 (8B/lane, 16 lanes/row).
// ---------------------------------------------------------------------------

#define HID 64
#define DSTRIDE 16  // ints: one atomic counter per 64B line

typedef __attribute__((ext_vector_type(8))) short short8;   // 8 bf16 (4 VGPR)
typedef __attribute__((ext_vector_type(4))) float floatx4;  // MFMA acc

__device__ __forceinline__ unsigned short f2bf(float f) {
    union { float f; unsigned u; } v; v.f = f;
    unsigned r = v.u + 0x7FFF + ((v.u >> 16) & 1);  // round-to-nearest-even
    return (unsigned short)(r >> 16);
}
__device__ __forceinline__ float bf2f(unsigned short u) {
    union { unsigned u; float f; } v; v.u = ((unsigned)u) << 16;
    return v.f;
}
__device__ __forceinline__ unsigned pack_bf2(float a, float b) {
    union { __hip_bfloat162 h; unsigned u; } cv;
    cv.h = __float22bfloat162_rn(make_float2(a, b));  // v_cvt_pk_bf16_f32
    return cv.u;
}

// ---------------- CSR build ----------------

__global__ __launch_bounds__(256)
void k_hist(const int* __restrict__ edst, int* __restrict__ deg_s,
            int* __restrict__ rank, int E) {
    int e = blockIdx.x * 256 + threadIdx.x;
    if (e < E) rank[e] = atomicAdd(&deg_s[(size_t)edst[e] * DSTRIDE], 1);
}

// scans 1024 strided counters per block; also writes compact deg_c
__global__ __launch_bounds__(256)
void k_scan1(const int* __restrict__ deg_s, int* __restrict__ deg_c,
             int* __restrict__ offs, int* __restrict__ bsums, int n) {
    __shared__ int lds[256];
    int t = threadIdx.x;
    int base = blockIdx.x * 1024 + t * 4;
    int v0 = 0, v1 = 0, v2 = 0, v3 = 0;
    if (base + 0 < n) v0 = deg_s[(size_t)(base + 0) * DSTRIDE];
    if (base + 1 < n) v1 = deg_s[(size_t)(base + 1) * DSTRIDE];
    if (base + 2 < n) v2 = deg_s[(size_t)(base + 2) * DSTRIDE];
    if (base + 3 < n) v3 = deg_s[(size_t)(base + 3) * DSTRIDE];
    int ts = v0 + v1 + v2 + v3;
    lds[t] = ts;
    __syncthreads();
    for (int off = 1; off < 256; off <<= 1) {
        int x = (t >= off) ? lds[t - off] : 0;
        __syncthreads();
        lds[t] += x;
        __syncthreads();
    }
    int excl = lds[t] - ts;
    if (base + 0 < n) { offs[base + 0] = excl;            deg_c[base + 0] = v0; }
    if (base + 1 < n) { offs[base + 1] = excl + v0;       deg_c[base + 1] = v1; }
    if (base + 2 < n) { offs[base + 2] = excl + v0 + v1;  deg_c[base + 2] = v2; }
    if (base + 3 < n) { offs[base + 3] = excl + v0 + v1 + v2; deg_c[base + 3] = v3; }
    if (t == 255) bsums[blockIdx.x] = lds[255];
}

__global__ __launch_bounds__(256)
void k_scan2(int* __restrict__ bsums, int nb) {
    __shared__ int lds[256];
    int t = threadIdx.x;
    int v = (t < nb) ? bsums[t] : 0;
    lds[t] = v;
    __syncthreads();
    for (int off = 1; off < 256; off <<= 1) {
        int x = (t >= off) ? lds[t - off] : 0;
        __syncthreads();
        lds[t] += x;
        __syncthreads();
    }
    if (t < nb) bsums[t] = lds[t] - v;
}

__global__ __launch_bounds__(256)
void k_scan3(int* __restrict__ offs, const int* __restrict__ bsums, int n) {
    int i = blockIdx.x * 256 + threadIdx.x;
    if (i < n) offs[i] += bsums[i >> 10];
}

__global__ __launch_bounds__(256)
void k_scatter(const int* __restrict__ esrc, const int* __restrict__ edst,
               const int* __restrict__ offs, const int* __restrict__ rank,
               int* __restrict__ sorted, int E) {
    int e = blockIdx.x * 256 + threadIdx.x;
    if (e < E) {
        int d = edst[e];
        sorted[offs[d] + rank[e]] = esrc[e];
    }
}

// ---------------- W cast: Wcb1 = bf16([Wl1;Wr1]) 128x128, Wcb2 = bf16([Wl2;Wr2]) 128x64

__global__ __launch_bounds__(256)
void k_castw(const float* __restrict__ Wl1, const float* __restrict__ Wr1,
             const float* __restrict__ Wl2, const float* __restrict__ Wr2,
             unsigned short* __restrict__ Wcb1, unsigned short* __restrict__ Wcb2) {
    int i = blockIdx.x * 256 + threadIdx.x;
    if (i < 16384) {
        Wcb1[i] = f2bf(i < 8192 ? Wl1[i] : Wr1[i - 8192]);
    } else if (i < 24576) {
        int j = i - 16384;
        Wcb2[j] = f2bf(j < 4096 ? Wl2[j] : Wr2[j - 4096]);
    }
}

// ---------------- MFMA dual GEMM: [P|Q] = A @ [Wl;Wr]^T ----------------
// Wave computes 16 rows x 64 cols (half=0 -> P bf16, half=1 -> Q f32).
// B-frags held in registers across a grid-stride row-tile loop.
// A is f32 (layer 1, cvt in-flight) or bf16 (layer 2).

template <int K, bool AF32>
__global__ __launch_bounds__(256, 2)
void gemm_mfma(const void* __restrict__ Xv, const unsigned short* __restrict__ Wcb,
               unsigned short* __restrict__ Pb, float* __restrict__ Qc, int N) {
    const int lane = threadIdx.x & 63;
    const int m = lane & 15;        // row (A) / col (B) within tile
    const int q = lane >> 4;        // k-quad
    const int gw = blockIdx.x * 4 + (threadIdx.x >> 6);
    const int half = gw & 1;        // 0 -> P (cols 0..63), 1 -> Q (cols 64..127)
    constexpr int KB = K / 32;

    short8 bf[KB][4];
#pragma unroll
    for (int kb = 0; kb < KB; ++kb)
#pragma unroll
        for (int ct = 0; ct < 4; ++ct) {
            int c = half * 64 + ct * 16 + m;
            bf[kb][ct] = *(const short8*)(Wcb + (size_t)c * K + kb * 32 + q * 8);
        }

    const int ntiles = (N + 15) >> 4;
    const int stride = gridDim.x * 2;  // waves per half
    for (int t = gw >> 1; t < ntiles; t += stride) {
        const int r0 = t << 4;
        int rr = r0 + m;
        if (rr >= N) rr = N - 1;
        floatx4 acc[4];
#pragma unroll
        for (int ct = 0; ct < 4; ++ct) acc[ct] = (floatx4){0.f, 0.f, 0.f, 0.f};

#pragma unroll
        for (int kb = 0; kb < KB; ++kb) {
            short8 a;
            if (AF32) {
                const float* xp = (const float*)Xv + (size_t)rr * K + kb * 32 + q * 8;
                float4 x0 = *(const float4*)xp;
                float4 x1 = *(const float4*)(xp + 4);
                union { unsigned u[4]; short8 s; } cv;
                cv.u[0] = pack_bf2(x0.x, x0.y);
                cv.u[1] = pack_bf2(x0.z, x0.w);
                cv.u[2] = pack_bf2(x1.x, x1.y);
                cv.u[3] = pack_bf2(x1.z, x1.w);
                a = cv.s;
            } else {
                a = *(const short8*)((const unsigned short*)Xv + (size_t)rr * K + kb * 32 + q * 8);
            }
#pragma unroll
            for (int ct = 0; ct < 4; ++ct)
                acc[ct] = __builtin_amdgcn_mfma_f32_16x16x32_bf16(a, bf[kb][ct], acc[ct], 0, 0, 0);
        }

        // C/D: col = ct*16 + m, row = r0 + q*4 + i
#pragma unroll
        for (int i = 0; i < 4; ++i) {
            int row = r0 + q * 4 + i;
            if (row < N) {
                if (half == 0) {
#pragma unroll
                    for (int ct = 0; ct < 4; ++ct)
                        Pb[(size_t)row * HID + ct * 16 + m] = f2bf(acc[ct][i]);
                } else {
#pragma unroll
                    for (int ct = 0; ct < 4; ++ct)
                        Qc[(size_t)row * HID + ct * 16 + m] = acc[ct][i];
                }
            }
        }
    }
}

// ------- aggregation: H = relu(mean_{s in N(n)} P[s] + bias + Qin[n]) -------
// 4 nodes per wave (16 lanes/node), lane = 4-channel group (uint2 loads).

__global__ __launch_bounds__(256)
void k_agg(const uint2* __restrict__ P16, const float4* __restrict__ Qin4,
           const float4* __restrict__ bias4, const int* __restrict__ offs,
           const int* __restrict__ deg, const int* __restrict__ sorted,
           uint2* __restrict__ H16, int N) {
    int node = blockIdx.x * 16 + (threadIdx.x >> 4);
    int c16 = threadIdx.x & 15;
    if (node >= N) return;
    int off = offs[node];
    int c = deg[node];
    float a0 = 0.f, a1 = 0.f, a2 = 0.f, a3 = 0.f;
    int i = 0;
    for (; i + 3 < c; i += 4) {
        int s0 = sorted[off + i];
        int s1 = sorted[off + i + 1];
        int s2 = sorted[off + i + 2];
        int s3 = sorted[off + i + 3];
        uint2 u0 = P16[(size_t)s0 * 16 + c16];
        uint2 u1 = P16[(size_t)s1 * 16 + c16];
        uint2 u2 = P16[(size_t)s2 * 16 + c16];
        uint2 u3 = P16[(size_t)s3 * 16 + c16];
        a0 += (bf2f((unsigned short)u0.x) + bf2f((unsigned short)u1.x)) +
              (bf2f((unsigned short)u2.x) + bf2f((unsigned short)u3.x));
        a1 += (bf2f((unsigned short)(u0.x >> 16)) + bf2f((unsigned short)(u1.x >> 16))) +
              (bf2f((unsigned short)(u2.x >> 16)) + bf2f((unsigned short)(u3.x >> 16)));
        a2 += (bf2f((unsigned short)u0.y) + bf2f((unsigned short)u1.y)) +
              (bf2f((unsigned short)u2.y) + bf2f((unsigned short)u3.y));
        a3 += (bf2f((unsigned short)(u0.y >> 16)) + bf2f((unsigned short)(u1.y >> 16))) +
              (bf2f((unsigned short)(u2.y >> 16)) + bf2f((unsigned short)(u3.y >> 16)));
    }
    for (; i < c; ++i) {
        uint2 u = P16[(size_t)sorted[off + i] * 16 + c16];
        a0 += bf2f((unsigned short)u.x);
        a1 += bf2f((unsigned short)(u.x >> 16));
        a2 += bf2f((unsigned short)u.y);
        a3 += bf2f((unsigned short)(u.y >> 16));
    }
    float inv = 1.0f / (float)(c > 0 ? c : 1);
    float4 bv = bias4[c16];
    float4 qv = Qin4[(size_t)node * 16 + c16];
    float v0 = a0 * inv + bv.x + qv.x;
    float v1 = a1 * inv + bv.y + qv.y;
    float v2 = a2 * inv + bv.z + qv.z;
    float v3 = a3 * inv + bv.w + qv.w;
    v0 = v0 > 0.f ? v0 : 0.f;
    v1 = v1 > 0.f ? v1 : 0.f;
    v2 = v2 > 0.f ? v2 : 0.f;
    v3 = v3 > 0.f ? v3 : 0.f;
    uint2 hp;
    hp.x = (unsigned)f2bf(v0) | ((unsigned)f2bf(v1) << 16);
    hp.y = (unsigned)f2bf(v2) | ((unsigned)f2bf(v3) << 16);
    H16[(size_t)node * 16 + c16] = hp;
}

// ---------------- query: out[q] = sigmoid(sum_c Z[s][c]*Z[d][c]) ----------------
// 4 queries per wave (16 lanes each), uint2 bf16x4 loads.

__global__ __launch_bounds__(256)
void k_query(const uint2* __restrict__ Z16, const int* __restrict__ src,
             const int* __restrict__ dst, float* __restrict__ out, int Q) {
    int qi = blockIdx.x * 16 + (threadIdx.x >> 4);
    int c16 = threadIdx.x & 15;
    if (qi >= Q) return;
    int s = src[qi];
    int d = dst[qi];
    uint2 us = Z16[(size_t)s * 16 + c16];
    uint2 ud = Z16[(size_t)d * 16 + c16];
    float v = bf2f((unsigned short)us.x) * bf2f((unsigned short)ud.x) +
              bf2f((unsigned short)(us.x >> 16)) * bf2f((unsigned short)(ud.x >> 16)) +
              bf2f((unsigned short)us.y) * bf2f((unsigned short)ud.y) +
              bf2f((unsigned short)(us.y >> 16)) * bf2f((unsigned short)(ud.y >> 16));
#pragma unroll
    for (int mres = 8; mres > 0; mres >>= 1) v += __shfl_xor(v, mres, 64);
    if (c16 == 0) out[qi] = 1.0f / (1.0f + __expf(-v));
}

// ---------------- launch ----------------

extern "C" void kernel_launch(void* const* d_in, const int* in_sizes, int n_in,
                              void* d_out, int out_size, void* d_ws, size_t ws_size,
                              hipStream_t stream) {
    const float* x    = (const float*)d_in[0];
    const int*   ei   = (const int*)d_in[1];
    const int*   qsrc = (const int*)d_in[2];
    const int*   qdst = (const int*)d_in[3];
    const float* Wl1  = (const float*)d_in[4];
    const float* bl1  = (const float*)d_in[5];
    const float* Wr1  = (const float*)d_in[6];
    const float* Wl2  = (const float*)d_in[7];
    const float* bl2  = (const float*)d_in[8];
    const float* Wr2  = (const float*)d_in[9];
    float* out = (float*)d_out;

    const int N = in_sizes[0] / 128;  // IN_CH = 128
    const int E = in_sizes[1] / 2;
    const int Q = in_sizes[2];

    const int* esrc = ei;
    const int* edst = ei + E;

    // workspace layout
    float*          Qc  = (float*)d_ws;                       // N x 64 f32 (root path)
    unsigned short* Pb  = (unsigned short*)(Qc + (size_t)N * HID);  // N x 64 bf16 messages
    unsigned short* Hb  = Pb + (size_t)N * HID;               // N x 64 bf16 h
    unsigned short* Zb  = Hb + (size_t)N * HID;               // N x 64 bf16 z
    int* deg_c  = (int*)(Zb + (size_t)N * HID);
    int* offs   = deg_c + N;
    int* bsums  = offs + N;                                   // up to 256
    int* sorted = bsums + 256;                                // E ints
    unsigned short* Wcb1 = (unsigned short*)(sorted + E);     // 128x128 bf16
    unsigned short* Wcb2 = Wcb1 + 16384;                      // 128x64 bf16
    // aliases (dead until gemm1 writes them):
    int* rank  = (int*)Pb;   // E ints <= 2*N*HID bytes
    int* deg_s = (int*)Qc;   // N*DSTRIDE ints = N*64B <= N*HID*4B

    const int gE = (E + 255) / 256;
    const int nblk = (N + 1023) / 1024;  // <= 256
    const int gN = (N + 255) / 256;
    const int gG = 640;                  // grid-stride MFMA gemm
    const int gA = (N + 15) / 16;        // 4 nodes/wave, 4 waves/block
    const int gQ = (Q + 15) / 16;

    hipMemsetAsync(deg_s, 0, sizeof(int) * (size_t)N * DSTRIDE, stream);
    k_castw<<<96, 256, 0, stream>>>(Wl1, Wr1, Wl2, Wr2, Wcb1, Wcb2);
    k_hist<<<gE, 256, 0, stream>>>(edst, deg_s, rank, E);
    k_scan1<<<nblk, 256, 0, stream>>>(deg_s, deg_c, offs, bsums, N);
    k_scan2<<<1, 256, 0, stream>>>(bsums, nblk);
    k_scan3<<<gN, 256, 0, stream>>>(offs, bsums, N);
    k_scatter<<<gE, 256, 0, stream>>>(esrc, edst, offs, rank, sorted, E);

    // layer 1: Pb = bf16(x@Wl1^T), Qc = x@Wr1^T; Hb = bf16(relu(mean+b+Qc))
    gemm_mfma<128, true><<<gG, 256, 0, stream>>>(x, Wcb1, Pb, Qc, N);
    k_agg<<<gA, 256, 0, stream>>>((const uint2*)Pb, (const float4*)Qc,
                                  (const float4*)bl1, offs, deg_c, sorted,
                                  (uint2*)Hb, N);

    // layer 2: Pb = bf16(Hb@Wl2^T), Qc = Hb@Wr2^T; Zb = bf16(relu(mean+b+Qc))
    gemm_mfma<64, false><<<gG, 256, 0, stream>>>(Hb, Wcb2, Pb, Qc, N);
    k_agg<<<gA, 256, 0, stream>>>((const uint2*)Pb, (const float4*)Qc,
                                  (const float4*)bl2, offs, deg_c, sorted,
                                  (uint2*)Zb, N);

    // queries
    k_query<<<gQ, 256, 0, stream>>>((const uint2*)Zb, qsrc, qdst, out, Q);
}

// Round 8
// 269.163 us; speedup vs baseline: 2.0314x; 1.2048x over previous
//
#include <hip/hip_runtime.h>
#include <hip/hip_bf16.h>
#include <math.h>

// ---------------------------------------------------------------------------
// GNN link predictor: 2-layer GraphSAGE (mean agg) + dot-product + sigmoid.
//  - transform-then-aggregate (mean is linear) -> aggregate in 64-dim space
//  - GEMMs on MFMA (16x16x32 bf16, fp32 accum), W-frags register-resident
//  - R8: CSR build rewritten as 2-level LDS counting sort (bucket = dst>>8).
//    R6/R7 showed 1.6M device-scope returning atomicAdds are a HW wall
//    (24.6 G/s memory-side RMW, insensitive to counter padding). New chain
//    has ZERO global atomics: LDS histograms + deterministic scans.
//  - k_agg/k_query: 4 rows/wave, uint2 (bf16x4) gather lanes.
// ---------------------------------------------------------------------------

#define HID 64
#define G_BLK 512   // blocks in bucket passes A/C
#define NB_MAX 512  // max buckets (N <= 131072)

typedef __attribute__((ext_vector_type(8))) short short8;   // 8 bf16 (4 VGPR)
typedef __attribute__((ext_vector_type(4))) float floatx4;  // MFMA acc

__device__ __forceinline__ unsigned short f2bf(float f) {
    union { float f; unsigned u; } v; v.f = f;
    unsigned r = v.u + 0x7FFF + ((v.u >> 16) & 1);  // round-to-nearest-even
    return (unsigned short)(r >> 16);
}
__device__ __forceinline__ float bf2f(unsigned short u) {
    union { unsigned u; float f; } v; v.u = ((unsigned)u) << 16;
    return v.f;
}
__device__ __forceinline__ unsigned pack_bf2(float a, float b) {
    union { __hip_bfloat162 h; unsigned u; } cv;
    cv.h = __float22bfloat162_rn(make_float2(a, b));  // v_cvt_pk_bf16_f32
    return cv.u;
}

// ---------------- CSR build: 2-level LDS counting sort ----------------

// Pass A: per-block LDS histogram over buckets (dst>>8). cnt[k*G_BLK + b].
__global__ __launch_bounds__(256)
void k_bhist(const int* __restrict__ edst, int* __restrict__ cnt,
             int E, int NB, int CH) {
    __shared__ int lh[NB_MAX];
    const int b = blockIdx.x;
    for (int i = threadIdx.x; i < NB; i += 256) lh[i] = 0;
    __syncthreads();
    const int e0 = b * CH;
    const int e1 = min(E, e0 + CH);
    for (int e = e0 + threadIdx.x; e < e1; e += 256)
        atomicAdd(&lh[edst[e] >> 8], 1);  // LDS atomic
    __syncthreads();
    for (int k = threadIdx.x; k < NB; k += 256)
        cnt[(size_t)k * G_BLK + b] = lh[k];
}

// Pass B1: per-bucket exclusive scan over the G_BLK blocks (wave per bucket).
__global__ __launch_bounds__(256)
void k_bscan1(int* __restrict__ cnt, int* __restrict__ total, int NB) {
    int k = blockIdx.x * 4 + (threadIdx.x >> 6);
    int lane = threadIdx.x & 63;
    if (k >= NB) return;
    int* row = cnt + (size_t)k * G_BLK;
    const int base = lane * 8;  // 8 consecutive blocks per lane
    int v[8];
#pragma unroll
    for (int j = 0; j < 8; ++j) v[j] = row[base + j];
    int s = 0;
#pragma unroll
    for (int j = 0; j < 8; ++j) s += v[j];
    int inc = s;
#pragma unroll
    for (int off = 1; off < 64; off <<= 1) {
        int o = __shfl_up(inc, off, 64);
        if (lane >= off) inc += o;
    }
    int run = inc - s;  // exclusive prefix of this lane's chunk
#pragma unroll
    for (int j = 0; j < 8; ++j) { int t = v[j]; row[base + j] = run; run += t; }
    if (lane == 63) total[k] = run;
}

// Pass B2: exclusive scan of bucket totals -> base. One block, 512 threads.
__global__ __launch_bounds__(512)
void k_bscan2(const int* __restrict__ total, int* __restrict__ base, int NB) {
    __shared__ int lds[512];
    int t = threadIdx.x;
    int v = (t < NB) ? total[t] : 0;
    lds[t] = v;
    __syncthreads();
    for (int off = 1; off < 512; off <<= 1) {
        int x = (t >= off) ? lds[t - off] : 0;
        __syncthreads();
        lds[t] += x;
        __syncthreads();
    }
    if (t < NB) base[t] = lds[t] - v;
}

// Pass C: scatter edges into bucket segments via LDS cursors (no global atomics).
// payload = (dst&255)<<24 | src  (src < 2^24).
__global__ __launch_bounds__(256)
void k_bscatter(const int* __restrict__ esrc, const int* __restrict__ edst,
                const int* __restrict__ cnt, const int* __restrict__ base,
                int* __restrict__ ebuf, int E, int NB, int CH) {
    __shared__ int cur[NB_MAX];
    const int b = blockIdx.x;
    for (int k = threadIdx.x; k < NB; k += 256)
        cur[k] = base[k] + cnt[(size_t)k * G_BLK + b];
    __syncthreads();
    const int e0 = b * CH;
    const int e1 = min(E, e0 + CH);
    for (int e = e0 + threadIdx.x; e < e1; e += 256) {
        int d = edst[e];
        int slot = atomicAdd(&cur[d >> 8], 1);  // LDS atomic
        ebuf[slot] = ((d & 255) << 24) | esrc[e];
    }
}

// Pass D: per-bucket local counting sort -> sorted[], deg[], offs[].
__global__ __launch_bounds__(256)
void k_bfinal(const int* __restrict__ ebuf, const int* __restrict__ total,
              const int* __restrict__ base, int* __restrict__ sorted,
              int* __restrict__ deg, int* __restrict__ offs, int N) {
    __shared__ int h[256], loc[256], cur[256], sc[256];
    const int k = blockIdx.x;
    const int t = threadIdx.x;
    const int nk = total[k];
    const int bs = base[k];
    h[t] = 0;
    __syncthreads();
    for (int i = bs + t; i < bs + nk; i += 256)
        atomicAdd(&h[(ebuf[i] >> 24) & 255], 1);
    __syncthreads();
    int v = h[t];
    sc[t] = v;
    __syncthreads();
    for (int off = 1; off < 256; off <<= 1) {
        int x = (t >= off) ? sc[t - off] : 0;
        __syncthreads();
        sc[t] += x;
        __syncthreads();
    }
    loc[t] = sc[t] - v;
    cur[t] = sc[t] - v;
    __syncthreads();
    for (int i = bs + t; i < bs + nk; i += 256) {
        int pk = ebuf[i];
        int j = (pk >> 24) & 255;
        int r = atomicAdd(&cur[j], 1);  // LDS atomic
        sorted[bs + r] = pk & 0xFFFFFF;
    }
    int node = (k << 8) + t;
    if (node < N) {
        deg[node] = v;
        offs[node] = bs + loc[t];
    }
}

// ---------------- W cast: Wcb1 = bf16([Wl1;Wr1]) 128x128, Wcb2 = bf16([Wl2;Wr2]) 128x64

__global__ __launch_bounds__(256)
void k_castw(const float* __restrict__ Wl1, const float* __restrict__ Wr1,
             const float* __restrict__ Wl2, const float* __restrict__ Wr2,
             unsigned short* __restrict__ Wcb1, unsigned short* __restrict__ Wcb2) {
    int i = blockIdx.x * 256 + threadIdx.x;
    if (i < 16384) {
        Wcb1[i] = f2bf(i < 8192 ? Wl1[i] : Wr1[i - 8192]);
    } else if (i < 24576) {
        int j = i - 16384;
        Wcb2[j] = f2bf(j < 4096 ? Wl2[j] : Wr2[j - 4096]);
    }
}

// ---------------- MFMA dual GEMM: [P|Q] = A @ [Wl;Wr]^T ----------------
// Wave computes 16 rows x 64 cols (half=0 -> P bf16, half=1 -> Q f32).
// B-frags held in registers across a grid-stride row-tile loop.
// A is f32 (layer 1, cvt in-flight) or bf16 (layer 2).

template <int K, bool AF32>
__global__ __launch_bounds__(256, 2)
void gemm_mfma(const void* __restrict__ Xv, const unsigned short* __restrict__ Wcb,
               unsigned short* __restrict__ Pb, float* __restrict__ Qc, int N) {
    const int lane = threadIdx.x & 63;
    const int m = lane & 15;        // row (A) / col (B) within tile
    const int q = lane >> 4;        // k-quad
    const int gw = blockIdx.x * 4 + (threadIdx.x >> 6);
    const int half = gw & 1;        // 0 -> P (cols 0..63), 1 -> Q (cols 64..127)
    constexpr int KB = K / 32;

    short8 bf[KB][4];
#pragma unroll
    for (int kb = 0; kb < KB; ++kb)
#pragma unroll
        for (int ct = 0; ct < 4; ++ct) {
            int c = half * 64 + ct * 16 + m;
            bf[kb][ct] = *(const short8*)(Wcb + (size_t)c * K + kb * 32 + q * 8);
        }

    const int ntiles = (N + 15) >> 4;
    const int stride = gridDim.x * 2;  // waves per half
    for (int t = gw >> 1; t < ntiles; t += stride) {
        const int r0 = t << 4;
        int rr = r0 + m;
        if (rr >= N) rr = N - 1;
        floatx4 acc[4];
#pragma unroll
        for (int ct = 0; ct < 4; ++ct) acc[ct] = (floatx4){0.f, 0.f, 0.f, 0.f};

#pragma unroll
        for (int kb = 0; kb < KB; ++kb) {
            short8 a;
            if (AF32) {
                const float* xp = (const float*)Xv + (size_t)rr * K + kb * 32 + q * 8;
                float4 x0 = *(const float4*)xp;
                float4 x1 = *(const float4*)(xp + 4);
                union { unsigned u[4]; short8 s; } cv;
                cv.u[0] = pack_bf2(x0.x, x0.y);
                cv.u[1] = pack_bf2(x0.z, x0.w);
                cv.u[2] = pack_bf2(x1.x, x1.y);
                cv.u[3] = pack_bf2(x1.z, x1.w);
                a = cv.s;
            } else {
                a = *(const short8*)((const unsigned short*)Xv + (size_t)rr * K + kb * 32 + q * 8);
            }
#pragma unroll
            for (int ct = 0; ct < 4; ++ct)
                acc[ct] = __builtin_amdgcn_mfma_f32_16x16x32_bf16(a, bf[kb][ct], acc[ct], 0, 0, 0);
        }

        // C/D: col = ct*16 + m, row = r0 + q*4 + i
#pragma unroll
        for (int i = 0; i < 4; ++i) {
            int row = r0 + q * 4 + i;
            if (row < N) {
                if (half == 0) {
#pragma unroll
                    for (int ct = 0; ct < 4; ++ct)
                        Pb[(size_t)row * HID + ct * 16 + m] = f2bf(acc[ct][i]);
                } else {
#pragma unroll
                    for (int ct = 0; ct < 4; ++ct)
                        Qc[(size_t)row * HID + ct * 16 + m] = acc[ct][i];
                }
            }
        }
    }
}

// ------- aggregation: H = relu(mean_{s in N(n)} P[s] + bias + Qin[n]) -------
// 4 nodes per wave (16 lanes/node), lane = 4-channel group (uint2 loads).

__global__ __launch_bounds__(256)
void k_agg(const uint2* __restrict__ P16, const float4* __restrict__ Qin4,
           const float4* __restrict__ bias4, const int* __restrict__ offs,
           const int* __restrict__ deg, const int* __restrict__ sorted,
           uint2* __restrict__ H16, int N) {
    int node = blockIdx.x * 16 + (threadIdx.x >> 4);
    int c16 = threadIdx.x & 15;
    if (node >= N) return;
    int off = offs[node];
    int c = deg[node];
    float a0 = 0.f, a1 = 0.f, a2 = 0.f, a3 = 0.f;
    int i = 0;
    for (; i + 3 < c; i += 4) {
        int s0 = sorted[off + i];
        int s1 = sorted[off + i + 1];
        int s2 = sorted[off + i + 2];
        int s3 = sorted[off + i + 3];
        uint2 u0 = P16[(size_t)s0 * 16 + c16];
        uint2 u1 = P16[(size_t)s1 * 16 + c16];
        uint2 u2 = P16[(size_t)s2 * 16 + c16];
        uint2 u3 = P16[(size_t)s3 * 16 + c16];
        a0 += (bf2f((unsigned short)u0.x) + bf2f((unsigned short)u1.x)) +
              (bf2f((unsigned short)u2.x) + bf2f((unsigned short)u3.x));
        a1 += (bf2f((unsigned short)(u0.x >> 16)) + bf2f((unsigned short)(u1.x >> 16))) +
              (bf2f((unsigned short)(u2.x >> 16)) + bf2f((unsigned short)(u3.x >> 16)));
        a2 += (bf2f((unsigned short)u0.y) + bf2f((unsigned short)u1.y)) +
              (bf2f((unsigned short)u2.y) + bf2f((unsigned short)u3.y));
        a3 += (bf2f((unsigned short)(u0.y >> 16)) + bf2f((unsigned short)(u1.y >> 16))) +
              (bf2f((unsigned short)(u2.y >> 16)) + bf2f((unsigned short)(u3.y >> 16)));
    }
    for (; i < c; ++i) {
        uint2 u = P16[(size_t)sorted[off + i] * 16 + c16];
        a0 += bf2f((unsigned short)u.x);
        a1 += bf2f((unsigned short)(u.x >> 16));
        a2 += bf2f((unsigned short)u.y);
        a3 += bf2f((unsigned short)(u.y >> 16));
    }
    float inv = 1.0f / (float)(c > 0 ? c : 1);
    float4 bv = bias4[c16];
    float4 qv = Qin4[(size_t)node * 16 + c16];
    float v0 = a0 * inv + bv.x + qv.x;
    float v1 = a1 * inv + bv.y + qv.y;
    float v2 = a2 * inv + bv.z + qv.z;
    float v3 = a3 * inv + bv.w + qv.w;
    v0 = v0 > 0.f ? v0 : 0.f;
    v1 = v1 > 0.f ? v1 : 0.f;
    v2 = v2 > 0.f ? v2 : 0.f;
    v3 = v3 > 0.f ? v3 : 0.f;
    uint2 hp;
    hp.x = (unsigned)f2bf(v0) | ((unsigned)f2bf(v1) << 16);
    hp.y = (unsigned)f2bf(v2) | ((unsigned)f2bf(v3) << 16);
    H16[(size_t)node * 16 + c16] = hp;
}

// ---------------- query: out[q] = sigmoid(sum_c Z[s][c]*Z[d][c]) ----------------
// 4 queries per wave (16 lanes each), uint2 bf16x4 loads.

__global__ __launch_bounds__(256)
void k_query(const uint2* __restrict__ Z16, const int* __restrict__ src,
             const int* __restrict__ dst, float* __restrict__ out, int Q) {
    int qi = blockIdx.x * 16 + (threadIdx.x >> 4);
    int c16 = threadIdx.x & 15;
    if (qi >= Q) return;
    int s = src[qi];
    int d = dst[qi];
    uint2 us = Z16[(size_t)s * 16 + c16];
    uint2 ud = Z16[(size_t)d * 16 + c16];
    float v = bf2f((unsigned short)us.x) * bf2f((unsigned short)ud.x) +
              bf2f((unsigned short)(us.x >> 16)) * bf2f((unsigned short)(ud.x >> 16)) +
              bf2f((unsigned short)us.y) * bf2f((unsigned short)ud.y) +
              bf2f((unsigned short)(us.y >> 16)) * bf2f((unsigned short)(ud.y >> 16));
#pragma unroll
    for (int mres = 8; mres > 0; mres >>= 1) v += __shfl_xor(v, mres, 64);
    if (c16 == 0) out[qi] = 1.0f / (1.0f + __expf(-v));
}

// ---------------- launch ----------------

extern "C" void kernel_launch(void* const* d_in, const int* in_sizes, int n_in,
                              void* d_out, int out_size, void* d_ws, size_t ws_size,
                              hipStream_t stream) {
    const float* x    = (const float*)d_in[0];
    const int*   ei   = (const int*)d_in[1];
    const int*   qsrc = (const int*)d_in[2];
    const int*   qdst = (const int*)d_in[3];
    const float* Wl1  = (const float*)d_in[4];
    const float* bl1  = (const float*)d_in[5];
    const float* Wr1  = (const float*)d_in[6];
    const float* Wl2  = (const float*)d_in[7];
    const float* bl2  = (const float*)d_in[8];
    const float* Wr2  = (const float*)d_in[9];
    float* out = (float*)d_out;

    const int N = in_sizes[0] / 128;  // IN_CH = 128
    const int E = in_sizes[1] / 2;
    const int Q = in_sizes[2];

    const int* esrc = ei;
    const int* edst = ei + E;

    // workspace layout
    float*          Qc  = (float*)d_ws;                       // N x 64 f32 (root path)
    unsigned short* Pb  = (unsigned short*)(Qc + (size_t)N * HID);  // N x 64 bf16 messages
    unsigned short* Hb  = Pb + (size_t)N * HID;               // N x 64 bf16 h
    unsigned short* Zb  = Hb + (size_t)N * HID;               // N x 64 bf16 z
    int* deg_c  = (int*)(Zb + (size_t)N * HID);
    int* offs   = deg_c + N;
    int* total  = offs + N;                                   // NB_MAX
    int* base   = total + NB_MAX;                             // NB_MAX
    int* sorted = base + NB_MAX;                              // E ints
    unsigned short* Wcb1 = (unsigned short*)(sorted + E);     // 128x128 bf16
    unsigned short* Wcb2 = Wcb1 + 16384;                      // 128x64 bf16
    // aliases (regions dead until gemm1 writes them):
    int* cnt  = (int*)Qc;   // NB*G_BLK ints <= 512*512*4B = 1MB << N*HID*4B
    int* ebuf = (int*)Pb;   // E ints = 6.4MB <= N*HID*2B = 12.8MB

    const int NB = (N + 255) >> 8;            // buckets (<= NB_MAX)
    const int CH = (E + G_BLK - 1) / G_BLK;   // edges per bucket-pass block
    const int gG = 640;                       // grid-stride MFMA gemm
    const int gA = (N + 15) / 16;             // 4 nodes/wave, 4 waves/block
    const int gQ = (Q + 15) / 16;

    // CSR build: zero global atomics
    k_castw<<<96, 256, 0, stream>>>(Wl1, Wr1, Wl2, Wr2, Wcb1, Wcb2);
    k_bhist<<<G_BLK, 256, 0, stream>>>(edst, cnt, E, NB, CH);
    k_bscan1<<<(NB + 3) / 4, 256, 0, stream>>>(cnt, total, NB);
    k_bscan2<<<1, 512, 0, stream>>>(total, base, NB);
    k_bscatter<<<G_BLK, 256, 0, stream>>>(esrc, edst, cnt, base, ebuf, E, NB, CH);
    k_bfinal<<<NB, 256, 0, stream>>>(ebuf, total, base, sorted, deg_c, offs, N);

    // layer 1: Pb = bf16(x@Wl1^T), Qc = x@Wr1^T; Hb = bf16(relu(mean+b+Qc))
    gemm_mfma<128, true><<<gG, 256, 0, stream>>>(x, Wcb1, Pb, Qc, N);
    k_agg<<<gA, 256, 0, stream>>>((const uint2*)Pb, (const float4*)Qc,
                                  (const float4*)bl1, offs, deg_c, sorted,
                                  (uint2*)Hb, N);

    // layer 2: Pb = bf16(Hb@Wl2^T), Qc = Hb@Wr2^T; Zb = bf16(relu(mean+b+Qc))
    gemm_mfma<64, false><<<gG, 256, 0, stream>>>(Hb, Wcb2, Pb, Qc, N);
    k_agg<<<gA, 256, 0, stream>>>((const uint2*)Pb, (const float4*)Qc,
                                  (const float4*)bl2, offs, deg_c, sorted,
                                  (uint2*)Zb, N);

    // queries
    k_query<<<gQ, 256, 0, stream>>>((const uint2*)Zb, qsrc, qdst, out, Q);
}

// Round 9
// 260.223 us; speedup vs baseline: 2.1012x; 1.0344x over previous
//
#include <hip/hip_runtime.h>
#include <hip/hip_bf16.h>
#include <math.h>

// ---------------------------------------------------------------------------
// GNN link predictor: 2-layer GraphSAGE (mean agg) + dot-product + sigmoid.
//  - transform-then-aggregate (mean is linear) -> aggregate in 64-dim space
//  - GEMMs on MFMA (16x16x32 bf16, fp32 accum), W-frags register-resident
//  - CSR build: 2-level LDS counting sort (bucket = dst>>8), ZERO global
//    atomics (R6/R7: 1.6M device-scope returning atomicAdds = 24.6G/s HW wall)
//  - R9: gathers widened to uint4 — 8 lanes x 16B = one 128B row per
//    8-lane group; half the gather instructions of R8's uint2 layout.
// ---------------------------------------------------------------------------

#define HID 64
#define G_BLK 512   // blocks in bucket passes A/C
#define NB_MAX 512  // max buckets (N <= 131072)

typedef __attribute__((ext_vector_type(8))) short short8;   // 8 bf16 (4 VGPR)
typedef __attribute__((ext_vector_type(4))) float floatx4;  // MFMA acc

__device__ __forceinline__ unsigned short f2bf(float f) {
    union { float f; unsigned u; } v; v.f = f;
    unsigned r = v.u + 0x7FFF + ((v.u >> 16) & 1);  // round-to-nearest-even
    return (unsigned short)(r >> 16);
}
__device__ __forceinline__ float bf2f(unsigned short u) {
    union { unsigned u; float f; } v; v.u = ((unsigned)u) << 16;
    return v.f;
}
__device__ __forceinline__ unsigned pack_bf2(float a, float b) {
    union { __hip_bfloat162 h; unsigned u; } cv;
    cv.h = __float22bfloat162_rn(make_float2(a, b));  // v_cvt_pk_bf16_f32
    return cv.u;
}
__device__ __forceinline__ void acc8(float* a, uint4 u) {
    a[0] += bf2f((unsigned short)u.x); a[1] += bf2f((unsigned short)(u.x >> 16));
    a[2] += bf2f((unsigned short)u.y); a[3] += bf2f((unsigned short)(u.y >> 16));
    a[4] += bf2f((unsigned short)u.z); a[5] += bf2f((unsigned short)(u.z >> 16));
    a[6] += bf2f((unsigned short)u.w); a[7] += bf2f((unsigned short)(u.w >> 16));
}

// ---------------- CSR build: 2-level LDS counting sort ----------------

// Pass A: per-block LDS histogram over buckets (dst>>8). cnt[k*G_BLK + b].
__global__ __launch_bounds__(256)
void k_bhist(const int* __restrict__ edst, int* __restrict__ cnt,
             int E, int NB, int CH) {
    __shared__ int lh[NB_MAX];
    const int b = blockIdx.x;
    for (int i = threadIdx.x; i < NB; i += 256) lh[i] = 0;
    __syncthreads();
    const int e0 = b * CH;
    const int e1 = min(E, e0 + CH);
    for (int e = e0 + threadIdx.x; e < e1; e += 256)
        atomicAdd(&lh[edst[e] >> 8], 1);  // LDS atomic
    __syncthreads();
    for (int k = threadIdx.x; k < NB; k += 256)
        cnt[(size_t)k * G_BLK + b] = lh[k];
}

// Pass B1: per-bucket exclusive scan over the G_BLK blocks (wave per bucket).
__global__ __launch_bounds__(256)
void k_bscan1(int* __restrict__ cnt, int* __restrict__ total, int NB) {
    int k = blockIdx.x * 4 + (threadIdx.x >> 6);
    int lane = threadIdx.x & 63;
    if (k >= NB) return;
    int* row = cnt + (size_t)k * G_BLK;
    const int base = lane * 8;  // 8 consecutive blocks per lane
    int v[8];
#pragma unroll
    for (int j = 0; j < 8; ++j) v[j] = row[base + j];
    int s = 0;
#pragma unroll
    for (int j = 0; j < 8; ++j) s += v[j];
    int inc = s;
#pragma unroll
    for (int off = 1; off < 64; off <<= 1) {
        int o = __shfl_up(inc, off, 64);
        if (lane >= off) inc += o;
    }
    int run = inc - s;  // exclusive prefix of this lane's chunk
#pragma unroll
    for (int j = 0; j < 8; ++j) { int t = v[j]; row[base + j] = run; run += t; }
    if (lane == 63) total[k] = run;
}

// Pass B2: exclusive scan of bucket totals -> base. One block, 512 threads.
__global__ __launch_bounds__(512)
void k_bscan2(const int* __restrict__ total, int* __restrict__ base, int NB) {
    __shared__ int lds[512];
    int t = threadIdx.x;
    int v = (t < NB) ? total[t] : 0;
    lds[t] = v;
    __syncthreads();
    for (int off = 1; off < 512; off <<= 1) {
        int x = (t >= off) ? lds[t - off] : 0;
        __syncthreads();
        lds[t] += x;
        __syncthreads();
    }
    if (t < NB) base[t] = lds[t] - v;
}

// Pass C: scatter edges into bucket segments via LDS cursors (no global atomics).
// payload = (dst&255)<<24 | src  (src < 2^24).
__global__ __launch_bounds__(256)
void k_bscatter(const int* __restrict__ esrc, const int* __restrict__ edst,
                const int* __restrict__ cnt, const int* __restrict__ base,
                int* __restrict__ ebuf, int E, int NB, int CH) {
    __shared__ int cur[NB_MAX];
    const int b = blockIdx.x;
    for (int k = threadIdx.x; k < NB; k += 256)
        cur[k] = base[k] + cnt[(size_t)k * G_BLK + b];
    __syncthreads();
    const int e0 = b * CH;
    const int e1 = min(E, e0 + CH);
    for (int e = e0 + threadIdx.x; e < e1; e += 256) {
        int d = edst[e];
        int slot = atomicAdd(&cur[d >> 8], 1);  // LDS atomic
        ebuf[slot] = ((d & 255) << 24) | esrc[e];
    }
}

// Pass D: per-bucket local counting sort -> sorted[], deg[], offs[].
__global__ __launch_bounds__(256)
void k_bfinal(const int* __restrict__ ebuf, const int* __restrict__ total,
              const int* __restrict__ base, int* __restrict__ sorted,
              int* __restrict__ deg, int* __restrict__ offs, int N) {
    __shared__ int h[256], loc[256], cur[256], sc[256];
    const int k = blockIdx.x;
    const int t = threadIdx.x;
    const int nk = total[k];
    const int bs = base[k];
    h[t] = 0;
    __syncthreads();
    for (int i = bs + t; i < bs + nk; i += 256)
        atomicAdd(&h[(ebuf[i] >> 24) & 255], 1);
    __syncthreads();
    int v = h[t];
    sc[t] = v;
    __syncthreads();
    for (int off = 1; off < 256; off <<= 1) {
        int x = (t >= off) ? sc[t - off] : 0;
        __syncthreads();
        sc[t] += x;
        __syncthreads();
    }
    loc[t] = sc[t] - v;
    cur[t] = sc[t] - v;
    __syncthreads();
    for (int i = bs + t; i < bs + nk; i += 256) {
        int pk = ebuf[i];
        int j = (pk >> 24) & 255;
        int r = atomicAdd(&cur[j], 1);  // LDS atomic
        sorted[bs + r] = pk & 0xFFFFFF;
    }
    int node = (k << 8) + t;
    if (node < N) {
        deg[node] = v;
        offs[node] = bs + loc[t];
    }
}

// ---------------- W cast: Wcb1 = bf16([Wl1;Wr1]) 128x128, Wcb2 = bf16([Wl2;Wr2]) 128x64

__global__ __launch_bounds__(256)
void k_castw(const float* __restrict__ Wl1, const float* __restrict__ Wr1,
             const float* __restrict__ Wl2, const float* __restrict__ Wr2,
             unsigned short* __restrict__ Wcb1, unsigned short* __restrict__ Wcb2) {
    int i = blockIdx.x * 256 + threadIdx.x;
    if (i < 16384) {
        Wcb1[i] = f2bf(i < 8192 ? Wl1[i] : Wr1[i - 8192]);
    } else if (i < 24576) {
        int j = i - 16384;
        Wcb2[j] = f2bf(j < 4096 ? Wl2[j] : Wr2[j - 4096]);
    }
}

// ---------------- MFMA dual GEMM: [P|Q] = A @ [Wl;Wr]^T ----------------
// Wave computes 16 rows x 64 cols (half=0 -> P bf16, half=1 -> Q f32).
// B-frags held in registers across a grid-stride row-tile loop.
// A is f32 (layer 1, cvt in-flight) or bf16 (layer 2).

template <int K, bool AF32>
__global__ __launch_bounds__(256, 2)
void gemm_mfma(const void* __restrict__ Xv, const unsigned short* __restrict__ Wcb,
               unsigned short* __restrict__ Pb, float* __restrict__ Qc, int N) {
    const int lane = threadIdx.x & 63;
    const int m = lane & 15;        // row (A) / col (B) within tile
    const int q = lane >> 4;        // k-quad
    const int gw = blockIdx.x * 4 + (threadIdx.x >> 6);
    const int half = gw & 1;        // 0 -> P (cols 0..63), 1 -> Q (cols 64..127)
    constexpr int KB = K / 32;

    short8 bf[KB][4];
#pragma unroll
    for (int kb = 0; kb < KB; ++kb)
#pragma unroll
        for (int ct = 0; ct < 4; ++ct) {
            int c = half * 64 + ct * 16 + m;
            bf[kb][ct] = *(const short8*)(Wcb + (size_t)c * K + kb * 32 + q * 8);
        }

    const int ntiles = (N + 15) >> 4;
    const int stride = gridDim.x * 2;  // waves per half
    for (int t = gw >> 1; t < ntiles; t += stride) {
        const int r0 = t << 4;
        int rr = r0 + m;
        if (rr >= N) rr = N - 1;
        floatx4 acc[4];
#pragma unroll
        for (int ct = 0; ct < 4; ++ct) acc[ct] = (floatx4){0.f, 0.f, 0.f, 0.f};

#pragma unroll
        for (int kb = 0; kb < KB; ++kb) {
            short8 a;
            if (AF32) {
                const float* xp = (const float*)Xv + (size_t)rr * K + kb * 32 + q * 8;
                float4 x0 = *(const float4*)xp;
                float4 x1 = *(const float4*)(xp + 4);
                union { unsigned u[4]; short8 s; } cv;
                cv.u[0] = pack_bf2(x0.x, x0.y);
                cv.u[1] = pack_bf2(x0.z, x0.w);
                cv.u[2] = pack_bf2(x1.x, x1.y);
                cv.u[3] = pack_bf2(x1.z, x1.w);
                a = cv.s;
            } else {
                a = *(const short8*)((const unsigned short*)Xv + (size_t)rr * K + kb * 32 + q * 8);
            }
#pragma unroll
            for (int ct = 0; ct < 4; ++ct)
                acc[ct] = __builtin_amdgcn_mfma_f32_16x16x32_bf16(a, bf[kb][ct], acc[ct], 0, 0, 0);
        }

        // C/D: col = ct*16 + m, row = r0 + q*4 + i
#pragma unroll
        for (int i = 0; i < 4; ++i) {
            int row = r0 + q * 4 + i;
            if (row < N) {
                if (half == 0) {
#pragma unroll
                    for (int ct = 0; ct < 4; ++ct)
                        Pb[(size_t)row * HID + ct * 16 + m] = f2bf(acc[ct][i]);
                } else {
#pragma unroll
                    for (int ct = 0; ct < 4; ++ct)
                        Qc[(size_t)row * HID + ct * 16 + m] = acc[ct][i];
                }
            }
        }
    }
}

// ------- aggregation: H = relu(mean_{s in N(n)} P[s] + bias + Qin[n]) -------
// 8 nodes per wave (8 lanes/node), lane = uint4 = 8 bf16 channels.
// One neighbor row = 8 lanes x 16B = one 128B cache line.

__global__ __launch_bounds__(256)
void k_agg(const uint4* __restrict__ P8, const float4* __restrict__ Qin4,
           const float4* __restrict__ bias4, const int* __restrict__ offs,
           const int* __restrict__ deg, const int* __restrict__ sorted,
           uint4* __restrict__ H8, int N) {
    int node = blockIdx.x * 32 + (threadIdx.x >> 3);
    int c8 = threadIdx.x & 7;
    if (node >= N) return;
    int off = offs[node];
    int c = deg[node];
    float a[8];
#pragma unroll
    for (int j = 0; j < 8; ++j) a[j] = 0.f;
    int i = 0;
    for (; i + 1 < c; i += 2) {
        int s0 = sorted[off + i];
        int s1 = sorted[off + i + 1];
        uint4 u0 = P8[(size_t)s0 * 8 + c8];
        uint4 u1 = P8[(size_t)s1 * 8 + c8];
        acc8(a, u0);
        acc8(a, u1);
    }
    if (i < c) acc8(a, P8[(size_t)sorted[off + i] * 8 + c8]);

    float inv = 1.0f / (float)(c > 0 ? c : 1);
    float4 b0 = bias4[c8 * 2], b1 = bias4[c8 * 2 + 1];
    float4 q0 = Qin4[(size_t)node * 16 + c8 * 2];
    float4 q1 = Qin4[(size_t)node * 16 + c8 * 2 + 1];
    float v0 = a[0] * inv + b0.x + q0.x;
    float v1 = a[1] * inv + b0.y + q0.y;
    float v2 = a[2] * inv + b0.z + q0.z;
    float v3 = a[3] * inv + b0.w + q0.w;
    float v4 = a[4] * inv + b1.x + q1.x;
    float v5 = a[5] * inv + b1.y + q1.y;
    float v6 = a[6] * inv + b1.z + q1.z;
    float v7 = a[7] * inv + b1.w + q1.w;
    v0 = fmaxf(v0, 0.f); v1 = fmaxf(v1, 0.f); v2 = fmaxf(v2, 0.f); v3 = fmaxf(v3, 0.f);
    v4 = fmaxf(v4, 0.f); v5 = fmaxf(v5, 0.f); v6 = fmaxf(v6, 0.f); v7 = fmaxf(v7, 0.f);
    uint4 hp;
    hp.x = (unsigned)f2bf(v0) | ((unsigned)f2bf(v1) << 16);
    hp.y = (unsigned)f2bf(v2) | ((unsigned)f2bf(v3) << 16);
    hp.z = (unsigned)f2bf(v4) | ((unsigned)f2bf(v5) << 16);
    hp.w = (unsigned)f2bf(v6) | ((unsigned)f2bf(v7) << 16);
    H8[(size_t)node * 8 + c8] = hp;
}

// ---------------- query: out[q] = sigmoid(sum_c Z[s][c]*Z[d][c]) ----------------
// 8 queries per wave (8 lanes each), uint4 bf16x8 loads.

__global__ __launch_bounds__(256)
void k_query(const uint4* __restrict__ Z8, const int* __restrict__ src,
             const int* __restrict__ dst, float* __restrict__ out, int Q) {
    int qi = blockIdx.x * 32 + (threadIdx.x >> 3);
    int c8 = threadIdx.x & 7;
    if (qi >= Q) return;
    int s = src[qi];
    int d = dst[qi];
    uint4 us = Z8[(size_t)s * 8 + c8];
    uint4 ud = Z8[(size_t)d * 8 + c8];
    float v =
        bf2f((unsigned short)us.x) * bf2f((unsigned short)ud.x) +
        bf2f((unsigned short)(us.x >> 16)) * bf2f((unsigned short)(ud.x >> 16)) +
        bf2f((unsigned short)us.y) * bf2f((unsigned short)ud.y) +
        bf2f((unsigned short)(us.y >> 16)) * bf2f((unsigned short)(ud.y >> 16)) +
        bf2f((unsigned short)us.z) * bf2f((unsigned short)ud.z) +
        bf2f((unsigned short)(us.z >> 16)) * bf2f((unsigned short)(ud.z >> 16)) +
        bf2f((unsigned short)us.w) * bf2f((unsigned short)ud.w) +
        bf2f((unsigned short)(us.w >> 16)) * bf2f((unsigned short)(ud.w >> 16));
#pragma unroll
    for (int mres = 4; mres > 0; mres >>= 1) v += __shfl_xor(v, mres, 64);
    if (c8 == 0) out[qi] = 1.0f / (1.0f + __expf(-v));
}

// ---------------- launch ----------------

extern "C" void kernel_launch(void* const* d_in, const int* in_sizes, int n_in,
                              void* d_out, int out_size, void* d_ws, size_t ws_size,
                              hipStream_t stream) {
    const float* x    = (const float*)d_in[0];
    const int*   ei   = (const int*)d_in[1];
    const int*   qsrc = (const int*)d_in[2];
    const int*   qdst = (const int*)d_in[3];
    const float* Wl1  = (const float*)d_in[4];
    const float* bl1  = (const float*)d_in[5];
    const float* Wr1  = (const float*)d_in[6];
    const float* Wl2  = (const float*)d_in[7];
    const float* bl2  = (const float*)d_in[8];
    const float* Wr2  = (const float*)d_in[9];
    float* out = (float*)d_out;

    const int N = in_sizes[0] / 128;  // IN_CH = 128
    const int E = in_sizes[1] / 2;
    const int Q = in_sizes[2];

    const int* esrc = ei;
    const int* edst = ei + E;

    // workspace layout
    float*          Qc  = (float*)d_ws;                       // N x 64 f32 (root path)
    unsigned short* Pb  = (unsigned short*)(Qc + (size_t)N * HID);  // N x 64 bf16 messages
    unsigned short* Hb  = Pb + (size_t)N * HID;               // N x 64 bf16 h
    unsigned short* Zb  = Hb + (size_t)N * HID;               // N x 64 bf16 z
    int* deg_c  = (int*)(Zb + (size_t)N * HID);
    int* offs   = deg_c + N;
    int* total  = offs + N;                                   // NB_MAX
    int* base   = total + NB_MAX;                             // NB_MAX
    int* sorted = base + NB_MAX;                              // E ints
    unsigned short* Wcb1 = (unsigned short*)(sorted + E);     // 128x128 bf16
    unsigned short* Wcb2 = Wcb1 + 16384;                      // 128x64 bf16
    // aliases (regions dead until gemm1 writes them):
    int* cnt  = (int*)Qc;   // NB*G_BLK ints <= 1MB << N*HID*4B
    int* ebuf = (int*)Pb;   // E ints = 6.4MB <= N*HID*2B = 12.8MB

    const int NB = (N + 255) >> 8;            // buckets (<= NB_MAX)
    const int CH = (E + G_BLK - 1) / G_BLK;   // edges per bucket-pass block
    const int gG = 640;                       // grid-stride MFMA gemm
    const int gA = (N + 31) / 32;             // 8 nodes/wave, 4 waves/block
    const int gQ = (Q + 31) / 32;

    // CSR build: zero global atomics
    k_castw<<<96, 256, 0, stream>>>(Wl1, Wr1, Wl2, Wr2, Wcb1, Wcb2);
    k_bhist<<<G_BLK, 256, 0, stream>>>(edst, cnt, E, NB, CH);
    k_bscan1<<<(NB + 3) / 4, 256, 0, stream>>>(cnt, total, NB);
    k_bscan2<<<1, 512, 0, stream>>>(total, base, NB);
    k_bscatter<<<G_BLK, 256, 0, stream>>>(esrc, edst, cnt, base, ebuf, E, NB, CH);
    k_bfinal<<<NB, 256, 0, stream>>>(ebuf, total, base, sorted, deg_c, offs, N);

    // layer 1: Pb = bf16(x@Wl1^T), Qc = x@Wr1^T; Hb = bf16(relu(mean+b+Qc))
    gemm_mfma<128, true><<<gG, 256, 0, stream>>>(x, Wcb1, Pb, Qc, N);
    k_agg<<<gA, 256, 0, stream>>>((const uint4*)Pb, (const float4*)Qc,
                                  (const float4*)bl1, offs, deg_c, sorted,
                                  (uint4*)Hb, N);

    // layer 2: Pb = bf16(Hb@Wl2^T), Qc = Hb@Wr2^T; Zb = bf16(relu(mean+b+Qc))
    gemm_mfma<64, false><<<gG, 256, 0, stream>>>(Hb, Wcb2, Pb, Qc, N);
    k_agg<<<gA, 256, 0, stream>>>((const uint4*)Pb, (const float4*)Qc,
                                  (const float4*)bl2, offs, deg_c, sorted,
                                  (uint4*)Zb, N);

    // queries
    k_query<<<gQ, 256, 0, stream>>>((const uint4*)Zb, qsrc, qdst, out, Q);
}